// Round 4
// baseline (380.914 us; speedup 1.0000x reference)
//
#include <hip/hip_runtime.h>
#include <math.h>

#define N_NODES 50000
#define N_EDGES 800000
#define N_GRAPHS 64
#define NEG 0.2f

typedef unsigned short us;
typedef us us2 __attribute__((ext_vector_type(2)));
typedef us us4 __attribute__((ext_vector_type(4)));
typedef us us8 __attribute__((ext_vector_type(8)));
typedef short bf16x8 __attribute__((ext_vector_type(8)));
typedef float f32x4 __attribute__((ext_vector_type(4)));

__device__ __forceinline__ us bf16rn(float f) {
  unsigned int u = __float_as_uint(f);
  u += 0x7FFFu + ((u >> 16) & 1u);
  return (us)(u >> 16);
}
__device__ __forceinline__ float bf2f(us h) {
  return __uint_as_float(((unsigned int)h) << 16);
}

// ---------------- W conversion (both layers in one launch) ----------------
__global__ __launch_bounds__(256) void convW_kernel(
    const float* __restrict__ W1, const float* __restrict__ W2,
    us* __restrict__ w1h, us* __restrict__ w1l,
    us* __restrict__ w2h, us* __restrict__ w2l) {
  int idx = blockIdx.x * 256 + threadIdx.x;
  const float* W; us *oh, *ol; int K, N, li;
  if (idx < 128 * 256) {
    W = W1; oh = w1h; ol = w1l; K = 128; N = 256; li = idx;
  } else if (idx < 2 * 128 * 256) {
    W = W2; oh = w2h; ol = w2l; K = 256; N = 128; li = idx - 128 * 256;
  } else return;
  int n = li / K, k = li - n * K;
  float f = W[(size_t)k * N + n];
  us h = bf16rn(f);
  oh[li] = h;
  ol[li] = bf16rn(f - bf2f(h));
}

// ---------------- MFMA GEMM, bf16x3 split precision ----------------
__global__ __launch_bounds__(256, 2) void gemm_bf16x3(
    const float* __restrict__ A, const us* __restrict__ Bth,
    const us* __restrict__ Btl, us* __restrict__ C, int M, int N, int K) {
  __shared__ us Ah[128][40];
  __shared__ us Al[128][40];
  __shared__ us Bh[128][40];
  __shared__ us Bl[128][40];
  int t = threadIdx.x;
  int m0 = blockIdx.x * 128;
  int n0 = blockIdx.y * 128;
  int w = t >> 6, l = t & 63;
  int wr = w >> 1, wc = w & 1;
  int l15 = l & 15, g = l >> 4;

  f32x4 acc[4][4] = {};

  for (int kb = 0; kb < K; kb += 32) {
    #pragma unroll
    for (int i = 0; i < 4; i++) {
      int slot = i * 256 + t;
      int row = slot >> 3, kq = slot & 7;
      float4 v = make_float4(0.f, 0.f, 0.f, 0.f);
      if (m0 + row < M) v = *(const float4*)&A[(size_t)(m0 + row) * K + kb + kq * 4];
      us h0 = bf16rn(v.x), h1 = bf16rn(v.y), h2 = bf16rn(v.z), h3 = bf16rn(v.w);
      us4 hv = {h0, h1, h2, h3};
      us4 lv = {bf16rn(v.x - bf2f(h0)), bf16rn(v.y - bf2f(h1)),
                bf16rn(v.z - bf2f(h2)), bf16rn(v.w - bf2f(h3))};
      *(us4*)&Ah[row][kq * 4] = hv;
      *(us4*)&Al[row][kq * 4] = lv;
    }
    #pragma unroll
    for (int i = 0; i < 2; i++) {
      int slot = i * 256 + t;
      int n = slot >> 2, kq = slot & 3;
      size_t gidx = (size_t)(n0 + n) * K + kb + kq * 8;
      *(us8*)&Bh[n][kq * 8] = *(const us8*)&Bth[gidx];
      *(us8*)&Bl[n][kq * 8] = *(const us8*)&Btl[gidx];
    }
    __syncthreads();

    bf16x8 af[4], al4[4], bf[4], bl4[4];
    #pragma unroll
    for (int i = 0; i < 4; i++) {
      af[i]  = *(const bf16x8*)&Ah[wr * 64 + i * 16 + l15][g * 8];
      al4[i] = *(const bf16x8*)&Al[wr * 64 + i * 16 + l15][g * 8];
      bf[i]  = *(const bf16x8*)&Bh[wc * 64 + i * 16 + l15][g * 8];
      bl4[i] = *(const bf16x8*)&Bl[wc * 64 + i * 16 + l15][g * 8];
    }
    #pragma unroll
    for (int i = 0; i < 4; i++)
      #pragma unroll
      for (int j = 0; j < 4; j++) {
        acc[i][j] = __builtin_amdgcn_mfma_f32_16x16x32_bf16(af[i], bf[j], acc[i][j], 0, 0, 0);
        acc[i][j] = __builtin_amdgcn_mfma_f32_16x16x32_bf16(af[i], bl4[j], acc[i][j], 0, 0, 0);
        acc[i][j] = __builtin_amdgcn_mfma_f32_16x16x32_bf16(al4[i], bf[j], acc[i][j], 0, 0, 0);
      }
    __syncthreads();
  }

  #pragma unroll
  for (int i = 0; i < 4; i++)
    #pragma unroll
    for (int j = 0; j < 4; j++)
      #pragma unroll
      for (int r = 0; r < 4; r++) {
        int row = m0 + wr * 64 + i * 16 + g * 4 + r;
        if (row < M) {
          int col = n0 + wc * 64 + j * 16 + l15;
          C[(size_t)row * N + col] = bf16rn(acc[i][j][r]);
        }
      }
}

// ---------------- logits layer 1 ----------------
__global__ __launch_bounds__(256) void logits1_kernel(
    const us* __restrict__ h1b, const float* __restrict__ a_src,
    const float* __restrict__ a_dst, float* __restrict__ al_s,
    float* __restrict__ al_d) {
  int idx = blockIdx.x * 256 + threadIdx.x;
  if (idx >= N_NODES * 4) return;
  int n = idx >> 2, h = idx & 3;
  const us* hp = &h1b[(size_t)n * 256 + h * 64];
  float ss = 0.f, sd = 0.f;
  #pragma unroll
  for (int i = 0; i < 8; i++) {
    us8 v = *(const us8*)&hp[i * 8];
    #pragma unroll
    for (int j = 0; j < 8; j++) {
      float f = bf2f(v[j]);
      ss += f * a_src[h * 64 + i * 8 + j];
      sd += f * a_dst[h * 64 + i * 8 + j];
    }
  }
  al_s[idx] = ss;
  al_d[idx] = sd;
}

// ---------------- logits layer 2 ----------------
__global__ __launch_bounds__(256) void logits2_kernel(
    const us* __restrict__ h2b, const float* __restrict__ a_src,
    const float* __restrict__ a_dst, float* __restrict__ al_s,
    float* __restrict__ al_d) {
  int n = blockIdx.x * 256 + threadIdx.x;
  if (n >= N_NODES) return;
  const us* hp = &h2b[(size_t)n * 128];
  float ss = 0.f, sd = 0.f;
  #pragma unroll
  for (int i = 0; i < 16; i++) {
    us8 v = *(const us8*)&hp[i * 8];
    #pragma unroll
    for (int j = 0; j < 8; j++) {
      float f = bf2f(v[j]);
      ss += f * a_src[i * 8 + j];
      sd += f * a_dst[i * 8 + j];
    }
  }
  al_s[n] = ss;
  al_d[n] = sd;
}

// ---------------- CSR build ----------------
__global__ __launch_bounds__(256) void count_kernel(const int* __restrict__ dst,
                                                    int* __restrict__ cnt) {
  int e = blockIdx.x * 256 + threadIdx.x;
  if (e < N_EDGES) atomicAdd(&cnt[dst[e]], 1);
}

__global__ __launch_bounds__(256) void scan1_kernel(const int* __restrict__ cnt,
                                                    int* __restrict__ itmp,
                                                    int* __restrict__ bsum) {
  int i = blockIdx.x * 256 + threadIdx.x;
  int v = (i < N_NODES) ? cnt[i] : 0;
  int lane = threadIdx.x & 63, w = threadIdx.x >> 6;
  int s = v;
  #pragma unroll
  for (int off = 1; off < 64; off <<= 1) {
    int tv = __shfl_up(s, off);
    if (lane >= off) s += tv;
  }
  __shared__ int wsum[4];
  if (lane == 63) wsum[w] = s;
  __syncthreads();
  int add = 0;
  for (int p = 0; p < w; p++) add += wsum[p];
  s += add;
  if (i < N_NODES) itmp[i] = s;
  if (threadIdx.x == 255) bsum[blockIdx.x] = s;
}

__global__ __launch_bounds__(256) void scan2_kernel(const int* __restrict__ bsum,
                                                    int* __restrict__ boff,
                                                    int nb) {
  int t = threadIdx.x;
  int v = (t < nb) ? bsum[t] : 0;
  int lane = t & 63, w = t >> 6;
  int s = v;
  #pragma unroll
  for (int off = 1; off < 64; off <<= 1) {
    int tv = __shfl_up(s, off);
    if (lane >= off) s += tv;
  }
  __shared__ int wsum[4];
  if (lane == 63) wsum[w] = s;
  __syncthreads();
  int add = 0;
  for (int p = 0; p < w; p++) add += wsum[p];
  s += add;
  if (t < nb) boff[t] = s - v;
}

__global__ __launch_bounds__(256) void scan3_kernel(const int* __restrict__ cnt,
                                                    const int* __restrict__ itmp,
                                                    const int* __restrict__ boff,
                                                    int* __restrict__ rowst,
                                                    int* __restrict__ cursor) {
  int i = blockIdx.x * 256 + threadIdx.x;
  if (i < N_NODES) {
    int excl = itmp[i] - cnt[i] + boff[i >> 8];
    rowst[i] = excl;
    cursor[i] = excl;
  }
  if (i == 0) rowst[N_NODES] = N_EDGES;
}

// scatter also records each edge's CSR slot in ep[e]
__global__ __launch_bounds__(256) void scatter_kernel(
    const int* __restrict__ src, const int* __restrict__ dst,
    int* __restrict__ cursor, int* __restrict__ csr_src,
    int* __restrict__ ep) {
  int e = blockIdx.x * 256 + threadIdx.x;
  if (e < N_EDGES) {
    int p = atomicAdd(&cursor[dst[e]], 1);
    csr_src[p] = src[e];
    ep[e] = p;
  }
}

// ---------------- edge weights, layer 1: one thread per (edge, head) ----------------
__global__ __launch_bounds__(256) void wgt1_kernel(
    const int* __restrict__ src, const int* __restrict__ dst,
    const int* __restrict__ ep, const float* __restrict__ al_s,
    const float* __restrict__ al_d, float* __restrict__ wcsr) {
  int idx = blockIdx.x * 256 + threadIdx.x;
  if (idx >= N_EDGES * 4) return;
  int e = idx >> 2, h = idx & 3;
  int s = src[e], d = dst[e];
  float v = al_s[s * 4 + h] + al_d[d * 4 + h];
  v = v > 0.f ? v : NEG * v;
  wcsr[(size_t)ep[e] * 4 + h] = __expf(v);
}

// ---------------- edge weights, layer 2: one thread per edge ----------------
__global__ __launch_bounds__(256) void wgt2_kernel(
    const int* __restrict__ src, const int* __restrict__ dst,
    const int* __restrict__ ep, const float* __restrict__ al_s,
    const float* __restrict__ al_d, float* __restrict__ wcsr) {
  int e = blockIdx.x * 256 + threadIdx.x;
  if (e >= N_EDGES) return;
  float v = al_s[src[e]] + al_d[dst[e]];
  v = v > 0.f ? v : NEG * v;
  wcsr[ep[e]] = __expf(v);
}

// ---------------- layer-1 aggregation: 2 half-waves per dst node ----------------
__device__ __forceinline__ void agg1_edge(int s, float wgt, int c0,
                                          const us* __restrict__ h1b,
                                          float& wsum, float& a0, float& a1) {
  us2 hv = *(const us2*)&h1b[(size_t)s * 256 + c0];
  wsum += wgt;
  a0 += wgt * bf2f(hv[0]);
  a1 += wgt * bf2f(hv[1]);
}

__global__ __launch_bounds__(256) void agg1_kernel(
    const us* __restrict__ h1b, const float* __restrict__ al_s,
    const float* __restrict__ al_d, const int* __restrict__ rowst,
    const int* __restrict__ csrc, const float* __restrict__ wcsr,
    const float* __restrict__ b1, float* __restrict__ out) {
  int wid = (blockIdx.x * 256 + threadIdx.x) >> 6;
  int lane = threadIdx.x & 63;
  int d = wid >> 1, hf = wid & 1;
  if (d >= N_NODES) return;
  int c0 = hf * 128 + lane * 2;
  int head = c0 >> 6;
  bool hi = lane >= 32;
  float wsum = 0.f, a0 = 0.f, a1 = 0.f;
  int beg = rowst[d], end = rowst[d + 1];
  {  // self-loop weight computed directly (once per node)
    float v = al_s[d * 4 + head] + al_d[d * 4 + head];
    v = v > 0.f ? v : NEG * v;
    agg1_edge(d, __expf(v), c0, h1b, wsum, a0, a1);
  }
  int j = beg;
  for (; j + 3 < end; j += 4) {
    int s0 = csrc[j], s1 = csrc[j + 1], s2 = csrc[j + 2], s3 = csrc[j + 3];
    float2 w0 = *(const float2*)&wcsr[(size_t)j * 4 + hf * 2];
    float2 w1 = *(const float2*)&wcsr[(size_t)(j + 1) * 4 + hf * 2];
    float2 w2 = *(const float2*)&wcsr[(size_t)(j + 2) * 4 + hf * 2];
    float2 w3 = *(const float2*)&wcsr[(size_t)(j + 3) * 4 + hf * 2];
    agg1_edge(s0, hi ? w0.y : w0.x, c0, h1b, wsum, a0, a1);
    agg1_edge(s1, hi ? w1.y : w1.x, c0, h1b, wsum, a0, a1);
    agg1_edge(s2, hi ? w2.y : w2.x, c0, h1b, wsum, a0, a1);
    agg1_edge(s3, hi ? w3.y : w3.x, c0, h1b, wsum, a0, a1);
  }
  for (; j < end; ++j) {
    float2 w0 = *(const float2*)&wcsr[(size_t)j * 4 + hf * 2];
    agg1_edge(csrc[j], hi ? w0.y : w0.x, c0, h1b, wsum, a0, a1);
  }
  float inv = 1.f / (wsum + 1e-16f);
  float2 bb = *(const float2*)&b1[c0];
  float o0 = a0 * inv + bb.x, o1 = a1 * inv + bb.y;
  o0 = o0 > 0.f ? o0 : expm1f(o0);
  o1 = o1 > 0.f ? o1 : expm1f(o1);
  *(float2*)&out[(size_t)d * 256 + c0] = make_float2(o0, o1);
}

// ---------------- layer-2 aggregation: one wave per dst node ----------------
__device__ __forceinline__ void agg2_edge(int s, float wgt, int lane,
                                          const us* __restrict__ h2b,
                                          float& wsum, float& a0, float& a1) {
  us2 hv = *(const us2*)&h2b[(size_t)s * 128 + lane * 2];
  wsum += wgt;
  a0 += wgt * bf2f(hv[0]);
  a1 += wgt * bf2f(hv[1]);
}

__global__ __launch_bounds__(256) void agg2_kernel(
    const us* __restrict__ h2b, const float* __restrict__ al_s,
    const float* __restrict__ al_d, const int* __restrict__ rowst,
    const int* __restrict__ csrc, const float* __restrict__ wcsr,
    const float* __restrict__ b2, float* __restrict__ out) {
  int d = (blockIdx.x * 256 + threadIdx.x) >> 6;
  int lane = threadIdx.x & 63;
  if (d >= N_NODES) return;
  float wsum = 0.f, a0 = 0.f, a1 = 0.f;
  int beg = rowst[d], end = rowst[d + 1];
  {
    float v = al_s[d] + al_d[d];
    v = v > 0.f ? v : NEG * v;
    agg2_edge(d, __expf(v), lane, h2b, wsum, a0, a1);
  }
  int j = beg;
  for (; j + 3 < end; j += 4) {
    int s0 = csrc[j], s1 = csrc[j + 1], s2 = csrc[j + 2], s3 = csrc[j + 3];
    float w0 = wcsr[j], w1 = wcsr[j + 1], w2 = wcsr[j + 2], w3 = wcsr[j + 3];
    agg2_edge(s0, w0, lane, h2b, wsum, a0, a1);
    agg2_edge(s1, w1, lane, h2b, wsum, a0, a1);
    agg2_edge(s2, w2, lane, h2b, wsum, a0, a1);
    agg2_edge(s3, w3, lane, h2b, wsum, a0, a1);
  }
  for (; j < end; ++j) agg2_edge(csrc[j], wcsr[j], lane, h2b, wsum, a0, a1);
  float inv = 1.f / (wsum + 1e-16f);
  float2 bb = *(const float2*)&b2[lane * 2];
  float o0 = a0 * inv + bb.x, o1 = a1 * inv + bb.y;
  o0 = o0 > 0.f ? o0 : expm1f(o0);
  o1 = o1 > 0.f ? o1 : expm1f(o1);
  *(float2*)&out[(size_t)d * 128 + lane * 2] = make_float2(o0, o1);
}

// ---------------- pooling ----------------
#define PNPB 128
__global__ __launch_bounds__(256) void pool_kernel(const float* __restrict__ y,
                                                   const int* __restrict__ batch,
                                                   float* __restrict__ psum) {
  int t = threadIdx.x;
  int lane32 = t & 31;
  int sub = t >> 5;
  int base = blockIdx.x * PNPB + sub * (PNPB / 8);
  int nend = base + PNPB / 8;
  if (nend > N_NODES) nend = N_NODES;
  float4 acc = make_float4(0.f, 0.f, 0.f, 0.f);
  int curg = -1;
  for (int n = base; n < nend; ++n) {
    int g = batch[n];
    if (g != curg) {
      if (curg >= 0) {
        float* p = &psum[curg * 128 + lane32 * 4];
        atomicAdd(p + 0, acc.x); atomicAdd(p + 1, acc.y);
        atomicAdd(p + 2, acc.z); atomicAdd(p + 3, acc.w);
      }
      acc = make_float4(0.f, 0.f, 0.f, 0.f);
      curg = g;
    }
    float4 v = *(const float4*)&y[(size_t)n * 128 + lane32 * 4];
    acc.x += v.x; acc.y += v.y; acc.z += v.z; acc.w += v.w;
  }
  if (curg >= 0) {
    float* p = &psum[curg * 128 + lane32 * 4];
    atomicAdd(p + 0, acc.x); atomicAdd(p + 1, acc.y);
    atomicAdd(p + 2, acc.z); atomicAdd(p + 3, acc.w);
  }
}

// ---------------- mean + FC + ReLU ----------------
__global__ __launch_bounds__(128) void fc_kernel(
    const float* __restrict__ psum, const int* __restrict__ batch,
    const float* __restrict__ fcW, const float* __restrict__ fcb,
    float* __restrict__ out) {
  __shared__ float pr[128];
  __shared__ int bounds[2];
  int g = blockIdx.x, c = threadIdx.x;
  if (c < 2) {
    int target = g + c;
    int lo = 0, hi = N_NODES;
    while (lo < hi) {
      int mid = (lo + hi) >> 1;
      if (batch[mid] < target) lo = mid + 1; else hi = mid;
    }
    bounds[c] = lo;
  }
  __syncthreads();
  float cnt = (float)(bounds[1] - bounds[0]);
  cnt = cnt > 1.f ? cnt : 1.f;
  pr[c] = psum[g * 128 + c] / cnt;
  __syncthreads();
  float s = fcb[c];
  #pragma unroll 8
  for (int k = 0; k < 128; k++) s += pr[k] * fcW[k * 128 + c];
  out[g * 128 + c] = fmaxf(s, 0.f);
}

extern "C" void kernel_launch(void* const* d_in, const int* in_sizes, int n_in,
                              void* d_out, int out_size, void* d_ws,
                              size_t ws_size, hipStream_t stream) {
  const float* x      = (const float*)d_in[0];
  const int*   ei     = (const int*)d_in[1];
  const int*   batch  = (const int*)d_in[2];
  const float* W1     = (const float*)d_in[3];
  const float* a1_src = (const float*)d_in[4];
  const float* a1_dst = (const float*)d_in[5];
  const float* b1     = (const float*)d_in[6];
  const float* W2     = (const float*)d_in[7];
  const float* a2_src = (const float*)d_in[8];
  const float* a2_dst = (const float*)d_in[9];
  const float* b2     = (const float*)d_in[10];
  const float* fc_W   = (const float*)d_in[11];
  const float* fc_b   = (const float*)d_in[12];
  float* out = (float*)d_out;

  const int* srcp = ei;
  const int* dstp = ei + N_EDGES;
  const int NB = (N_NODES + 255) / 256;  // 196

  // ---- workspace layout ----
  float* x2    = (float*)d_ws;                 // [50000*256]
  float* y     = x2 + (size_t)N_NODES * 256;   // [50000*128]
  float* al1s  = y + (size_t)N_NODES * 128;
  float* al1d  = al1s + N_NODES * 4;
  float* al2s  = al1d + N_NODES * 4;
  float* al2d  = al2s + N_NODES;
  float* psum  = al2d + N_NODES;               // [64*128]
  float* wcsr1 = psum + N_GRAPHS * 128;        // [800000*4]
  float* wcsr2 = wcsr1 + (size_t)N_EDGES * 4;  // [800000]
  us* h1b  = (us*)(wcsr2 + N_EDGES);           // [50000*256]
  us* h2b  = h1b + (size_t)N_NODES * 256;      // [50000*128]
  us* w1th = h2b + (size_t)N_NODES * 128;
  us* w1tl = w1th + 256 * 128;
  us* w2th = w1tl + 256 * 128;
  us* w2tl = w2th + 128 * 256;
  int* cnt    = (int*)(w2tl + 128 * 256);      // [50000]
  int* bsum   = cnt + N_NODES;
  int* boff   = bsum + 256;
  int* itmp   = boff + 256;
  int* rowst  = itmp + N_NODES;                // [50001]
  int* cursor = rowst + N_NODES + 8;
  int* ep     = cursor + N_NODES;              // [800000]
  int* csrc   = ep + N_EDGES;                  // [800000]
  size_t needed = (size_t)((char*)(csrc + N_EDGES) - (char*)d_ws);
  if (ws_size < needed) return;

  hipMemsetAsync(cnt, 0, N_NODES * sizeof(int), stream);
  hipMemsetAsync(psum, 0, N_GRAPHS * 128 * sizeof(float), stream);

  // CSR build
  count_kernel<<<(N_EDGES + 255) / 256, 256, 0, stream>>>(dstp, cnt);
  scan1_kernel<<<NB, 256, 0, stream>>>(cnt, itmp, bsum);
  scan2_kernel<<<1, 256, 0, stream>>>(bsum, boff, NB);
  scan3_kernel<<<NB, 256, 0, stream>>>(cnt, itmp, boff, rowst, cursor);
  scatter_kernel<<<(N_EDGES + 255) / 256, 256, 0, stream>>>(srcp, dstp, cursor, csrc, ep);

  // weight prep
  convW_kernel<<<(2 * 128 * 256 + 255) / 256, 256, 0, stream>>>(
      W1, W2, w1th, w1tl, w2th, w2tl);

  // layer 1
  gemm_bf16x3<<<dim3(391, 2), 256, 0, stream>>>(x, w1th, w1tl, h1b, N_NODES, 256, 128);
  logits1_kernel<<<(N_NODES * 4 + 255) / 256, 256, 0, stream>>>(h1b, a1_src, a1_dst, al1s, al1d);
  wgt1_kernel<<<(N_EDGES * 4 + 255) / 256, 256, 0, stream>>>(srcp, dstp, ep, al1s, al1d, wcsr1);
  agg1_kernel<<<(N_NODES * 2 * 64 + 255) / 256, 256, 0, stream>>>(
      h1b, al1s, al1d, rowst, csrc, wcsr1, b1, x2);

  // layer 2
  gemm_bf16x3<<<dim3(391, 1), 256, 0, stream>>>(x2, w2th, w2tl, h2b, N_NODES, 128, 256);
  logits2_kernel<<<(N_NODES + 255) / 256, 256, 0, stream>>>(h2b, a2_src, a2_dst, al2s, al2d);
  wgt2_kernel<<<(N_EDGES + 255) / 256, 256, 0, stream>>>(srcp, dstp, ep, al2s, al2d, wcsr2);
  agg2_kernel<<<(N_NODES + 3) / 4, 256, 0, stream>>>(h2b, al2s, al2d, rowst, csrc, wcsr2, b2, y);

  // pool + fc
  pool_kernel<<<(N_NODES + PNPB - 1) / PNPB, 256, 0, stream>>>(y, batch, psum);
  fc_kernel<<<N_GRAPHS, 128, 0, stream>>>(psum, batch, fc_W, fc_b, out);
}

// Round 5
// 338.975 us; speedup vs baseline: 1.1237x; 1.1237x over previous
//
#include <hip/hip_runtime.h>
#include <math.h>

#define N_NODES 50000
#define N_EDGES 800000
#define N_GRAPHS 64
#define NEG 0.2f

typedef unsigned short us;
typedef us us2 __attribute__((ext_vector_type(2)));
typedef us us4 __attribute__((ext_vector_type(4)));
typedef us us8 __attribute__((ext_vector_type(8)));
typedef short bf16x8 __attribute__((ext_vector_type(8)));
typedef float f32x4 __attribute__((ext_vector_type(4)));

__device__ __forceinline__ us bf16rn(float f) {
  unsigned int u = __float_as_uint(f);
  u += 0x7FFFu + ((u >> 16) & 1u);
  return (us)(u >> 16);
}
__device__ __forceinline__ float bf2f(us h) {
  return __uint_as_float(((unsigned int)h) << 16);
}

// ---------------- W conversion (both layers in one launch) ----------------
__global__ __launch_bounds__(256) void convW_kernel(
    const float* __restrict__ W1, const float* __restrict__ W2,
    us* __restrict__ w1h, us* __restrict__ w1l,
    us* __restrict__ w2h, us* __restrict__ w2l) {
  int idx = blockIdx.x * 256 + threadIdx.x;
  const float* W; us *oh, *ol; int K, N, li;
  if (idx < 128 * 256) {
    W = W1; oh = w1h; ol = w1l; K = 128; N = 256; li = idx;
  } else if (idx < 2 * 128 * 256) {
    W = W2; oh = w2h; ol = w2l; K = 256; N = 128; li = idx - 128 * 256;
  } else return;
  int n = li / K, k = li - n * K;
  float f = W[(size_t)k * N + n];
  us h = bf16rn(f);
  oh[li] = h;
  ol[li] = bf16rn(f - bf2f(h));
}

// ---------------- MFMA GEMM, bf16x3 split precision ----------------
__global__ __launch_bounds__(256, 2) void gemm_bf16x3(
    const float* __restrict__ A, const us* __restrict__ Bth,
    const us* __restrict__ Btl, us* __restrict__ C, int M, int N, int K) {
  __shared__ us Ah[128][40];
  __shared__ us Al[128][40];
  __shared__ us Bh[128][40];
  __shared__ us Bl[128][40];
  int t = threadIdx.x;
  int m0 = blockIdx.x * 128;
  int n0 = blockIdx.y * 128;
  int w = t >> 6, l = t & 63;
  int wr = w >> 1, wc = w & 1;
  int l15 = l & 15, g = l >> 4;

  f32x4 acc[4][4] = {};

  for (int kb = 0; kb < K; kb += 32) {
    #pragma unroll
    for (int i = 0; i < 4; i++) {
      int slot = i * 256 + t;
      int row = slot >> 3, kq = slot & 7;
      float4 v = make_float4(0.f, 0.f, 0.f, 0.f);
      if (m0 + row < M) v = *(const float4*)&A[(size_t)(m0 + row) * K + kb + kq * 4];
      us h0 = bf16rn(v.x), h1 = bf16rn(v.y), h2 = bf16rn(v.z), h3 = bf16rn(v.w);
      us4 hv = {h0, h1, h2, h3};
      us4 lv = {bf16rn(v.x - bf2f(h0)), bf16rn(v.y - bf2f(h1)),
                bf16rn(v.z - bf2f(h2)), bf16rn(v.w - bf2f(h3))};
      *(us4*)&Ah[row][kq * 4] = hv;
      *(us4*)&Al[row][kq * 4] = lv;
    }
    #pragma unroll
    for (int i = 0; i < 2; i++) {
      int slot = i * 256 + t;
      int n = slot >> 2, kq = slot & 3;
      size_t gidx = (size_t)(n0 + n) * K + kb + kq * 8;
      *(us8*)&Bh[n][kq * 8] = *(const us8*)&Bth[gidx];
      *(us8*)&Bl[n][kq * 8] = *(const us8*)&Btl[gidx];
    }
    __syncthreads();

    bf16x8 af[4], al4[4], bf[4], bl4[4];
    #pragma unroll
    for (int i = 0; i < 4; i++) {
      af[i]  = *(const bf16x8*)&Ah[wr * 64 + i * 16 + l15][g * 8];
      al4[i] = *(const bf16x8*)&Al[wr * 64 + i * 16 + l15][g * 8];
      bf[i]  = *(const bf16x8*)&Bh[wc * 64 + i * 16 + l15][g * 8];
      bl4[i] = *(const bf16x8*)&Bl[wc * 64 + i * 16 + l15][g * 8];
    }
    #pragma unroll
    for (int i = 0; i < 4; i++)
      #pragma unroll
      for (int j = 0; j < 4; j++) {
        acc[i][j] = __builtin_amdgcn_mfma_f32_16x16x32_bf16(af[i], bf[j], acc[i][j], 0, 0, 0);
        acc[i][j] = __builtin_amdgcn_mfma_f32_16x16x32_bf16(af[i], bl4[j], acc[i][j], 0, 0, 0);
        acc[i][j] = __builtin_amdgcn_mfma_f32_16x16x32_bf16(al4[i], bf[j], acc[i][j], 0, 0, 0);
      }
    __syncthreads();
  }

  #pragma unroll
  for (int i = 0; i < 4; i++)
    #pragma unroll
    for (int j = 0; j < 4; j++)
      #pragma unroll
      for (int r = 0; r < 4; r++) {
        int row = m0 + wr * 64 + i * 16 + g * 4 + r;
        if (row < M) {
          int col = n0 + wc * 64 + j * 16 + l15;
          C[(size_t)row * N + col] = bf16rn(acc[i][j][r]);
        }
      }
}

// ---------------- logits layer 1 ----------------
__global__ __launch_bounds__(256) void logits1_kernel(
    const us* __restrict__ h1b, const float* __restrict__ a_src,
    const float* __restrict__ a_dst, float* __restrict__ al_s,
    float* __restrict__ al_d) {
  int idx = blockIdx.x * 256 + threadIdx.x;
  if (idx >= N_NODES * 4) return;
  int n = idx >> 2, h = idx & 3;
  const us* hp = &h1b[(size_t)n * 256 + h * 64];
  float ss = 0.f, sd = 0.f;
  #pragma unroll
  for (int i = 0; i < 8; i++) {
    us8 v = *(const us8*)&hp[i * 8];
    #pragma unroll
    for (int j = 0; j < 8; j++) {
      float f = bf2f(v[j]);
      ss += f * a_src[h * 64 + i * 8 + j];
      sd += f * a_dst[h * 64 + i * 8 + j];
    }
  }
  al_s[idx] = ss;
  al_d[idx] = sd;
}

// ---------------- logits layer 2 ----------------
__global__ __launch_bounds__(256) void logits2_kernel(
    const us* __restrict__ h2b, const float* __restrict__ a_src,
    const float* __restrict__ a_dst, float* __restrict__ al_s,
    float* __restrict__ al_d) {
  int n = blockIdx.x * 256 + threadIdx.x;
  if (n >= N_NODES) return;
  const us* hp = &h2b[(size_t)n * 128];
  float ss = 0.f, sd = 0.f;
  #pragma unroll
  for (int i = 0; i < 16; i++) {
    us8 v = *(const us8*)&hp[i * 8];
    #pragma unroll
    for (int j = 0; j < 8; j++) {
      float f = bf2f(v[j]);
      ss += f * a_src[i * 8 + j];
      sd += f * a_dst[i * 8 + j];
    }
  }
  al_s[n] = ss;
  al_d[n] = sd;
}

// ---------------- CSR build ----------------
__global__ __launch_bounds__(256) void count_kernel(const int* __restrict__ dst,
                                                    int* __restrict__ cnt) {
  int e = blockIdx.x * 256 + threadIdx.x;
  if (e < N_EDGES) atomicAdd(&cnt[dst[e]], 1);
}

__global__ __launch_bounds__(256) void scan1_kernel(const int* __restrict__ cnt,
                                                    int* __restrict__ itmp,
                                                    int* __restrict__ bsum) {
  int i = blockIdx.x * 256 + threadIdx.x;
  int v = (i < N_NODES) ? cnt[i] : 0;
  int lane = threadIdx.x & 63, w = threadIdx.x >> 6;
  int s = v;
  #pragma unroll
  for (int off = 1; off < 64; off <<= 1) {
    int tv = __shfl_up(s, off);
    if (lane >= off) s += tv;
  }
  __shared__ int wsum[4];
  if (lane == 63) wsum[w] = s;
  __syncthreads();
  int add = 0;
  for (int p = 0; p < w; p++) add += wsum[p];
  s += add;
  if (i < N_NODES) itmp[i] = s;
  if (threadIdx.x == 255) bsum[blockIdx.x] = s;
}

__global__ __launch_bounds__(256) void scan2_kernel(const int* __restrict__ bsum,
                                                    int* __restrict__ boff,
                                                    int nb) {
  int t = threadIdx.x;
  int v = (t < nb) ? bsum[t] : 0;
  int lane = t & 63, w = t >> 6;
  int s = v;
  #pragma unroll
  for (int off = 1; off < 64; off <<= 1) {
    int tv = __shfl_up(s, off);
    if (lane >= off) s += tv;
  }
  __shared__ int wsum[4];
  if (lane == 63) wsum[w] = s;
  __syncthreads();
  int add = 0;
  for (int p = 0; p < w; p++) add += wsum[p];
  s += add;
  if (t < nb) boff[t] = s - v;
}

__global__ __launch_bounds__(256) void scan3_kernel(const int* __restrict__ cnt,
                                                    const int* __restrict__ itmp,
                                                    const int* __restrict__ boff,
                                                    int* __restrict__ rowst,
                                                    int* __restrict__ cursor) {
  int i = blockIdx.x * 256 + threadIdx.x;
  if (i < N_NODES) {
    int excl = itmp[i] - cnt[i] + boff[i >> 8];
    rowst[i] = excl;
    cursor[i] = excl;
  }
  if (i == 0) rowst[N_NODES] = N_EDGES;
}

__global__ __launch_bounds__(256) void scatter_kernel(
    const int* __restrict__ src, const int* __restrict__ dst,
    int* __restrict__ cursor, int* __restrict__ csr_src) {
  int e = blockIdx.x * 256 + threadIdx.x;
  if (e < N_EDGES) {
    int p = atomicAdd(&cursor[dst[e]], 1);
    csr_src[p] = src[e];
  }
}

// ---------------- layer-1 aggregation: one wave per node ----------------
// chunk of 16 edges: lane (k + 16h) computes weight of edge k for head h,
// k-loop redistributes via shfl (ds pipe), each lane gathers its 4 channels.
__global__ __launch_bounds__(256) void agg1_kernel(
    const us* __restrict__ h1b, const float* __restrict__ al_s,
    const float* __restrict__ al_d, const int* __restrict__ rowst,
    const int* __restrict__ csrc, const float* __restrict__ b1,
    float* __restrict__ out) {
  int d = (blockIdx.x * 256 + threadIdx.x) >> 6;
  int lane = threadIdx.x & 63;
  if (d >= N_NODES) return;
  int head = lane >> 4;
  int c0 = lane * 4;
  int wsel = lane & 48;  // shfl base for this lane's head group
  float ald = al_d[d * 4 + head];
  float wsum = 0.f, a0 = 0.f, a1 = 0.f, a2 = 0.f, a3 = 0.f;
  {  // self-loop
    float v = al_s[d * 4 + head] + ald;
    v = v > 0.f ? v : NEG * v;
    float w = __expf(v);
    us4 hv = *(const us4*)&h1b[(size_t)d * 256 + c0];
    wsum += w;
    a0 += w * bf2f(hv[0]); a1 += w * bf2f(hv[1]);
    a2 += w * bf2f(hv[2]); a3 += w * bf2f(hv[3]);
  }
  int beg = rowst[d], end = rowst[d + 1];
  for (int j = beg; j < end; j += 16) {
    int m = end - j;
    m = m < 16 ? m : 16;
    int el = lane & 15;
    int sv = csrc[j + (el < m ? el : 0)];
    float v = al_s[sv * 4 + head] + ald;
    v = v > 0.f ? v : NEG * v;
    float wv = __expf(v);
    #pragma unroll 4
    for (int k = 0; k < m; ++k) {
      int s = __shfl(sv, k);
      float w = __shfl(wv, k + wsel);
      us4 hv = *(const us4*)&h1b[(size_t)s * 256 + c0];
      wsum += w;
      a0 += w * bf2f(hv[0]); a1 += w * bf2f(hv[1]);
      a2 += w * bf2f(hv[2]); a3 += w * bf2f(hv[3]);
    }
  }
  float inv = 1.f / (wsum + 1e-16f);
  float4 bb = *(const float4*)&b1[c0];
  float o0 = a0 * inv + bb.x, o1 = a1 * inv + bb.y;
  float o2 = a2 * inv + bb.z, o3 = a3 * inv + bb.w;
  o0 = o0 > 0.f ? o0 : expm1f(o0);
  o1 = o1 > 0.f ? o1 : expm1f(o1);
  o2 = o2 > 0.f ? o2 : expm1f(o2);
  o3 = o3 > 0.f ? o3 : expm1f(o3);
  *(float4*)&out[(size_t)d * 256 + c0] = make_float4(o0, o1, o2, o3);
}

// ---------------- layer-2 aggregation: one wave per node, 64-edge chunks ----------------
__global__ __launch_bounds__(256) void agg2_kernel(
    const us* __restrict__ h2b, const float* __restrict__ al_s,
    const float* __restrict__ al_d, const int* __restrict__ rowst,
    const int* __restrict__ csrc, const float* __restrict__ b2,
    float* __restrict__ out) {
  int d = (blockIdx.x * 256 + threadIdx.x) >> 6;
  int lane = threadIdx.x & 63;
  if (d >= N_NODES) return;
  int c0 = lane * 2;
  float ald = al_d[d];
  float wsum = 0.f, a0 = 0.f, a1 = 0.f;
  {  // self-loop
    float v = al_s[d] + ald;
    v = v > 0.f ? v : NEG * v;
    float w = __expf(v);
    us2 hv = *(const us2*)&h2b[(size_t)d * 128 + c0];
    wsum += w;
    a0 += w * bf2f(hv[0]); a1 += w * bf2f(hv[1]);
  }
  int beg = rowst[d], end = rowst[d + 1];
  for (int j = beg; j < end; j += 64) {
    int m = end - j;
    m = m < 64 ? m : 64;
    int sv = csrc[j + (lane < m ? lane : 0)];
    float v = al_s[sv] + ald;
    v = v > 0.f ? v : NEG * v;
    float wv = __expf(v);
    #pragma unroll 4
    for (int k = 0; k < m; ++k) {
      int s = __shfl(sv, k);
      float w = __shfl(wv, k);
      us2 hv = *(const us2*)&h2b[(size_t)s * 128 + c0];
      wsum += w;
      a0 += w * bf2f(hv[0]); a1 += w * bf2f(hv[1]);
    }
  }
  float inv = 1.f / (wsum + 1e-16f);
  float2 bb = *(const float2*)&b2[c0];
  float o0 = a0 * inv + bb.x, o1 = a1 * inv + bb.y;
  o0 = o0 > 0.f ? o0 : expm1f(o0);
  o1 = o1 > 0.f ? o1 : expm1f(o1);
  *(float2*)&out[(size_t)d * 128 + c0] = make_float2(o0, o1);
}

// ---------------- pooling ----------------
#define PNPB 128
__global__ __launch_bounds__(256) void pool_kernel(const float* __restrict__ y,
                                                   const int* __restrict__ batch,
                                                   float* __restrict__ psum) {
  int t = threadIdx.x;
  int lane32 = t & 31;
  int sub = t >> 5;
  int base = blockIdx.x * PNPB + sub * (PNPB / 8);
  int nend = base + PNPB / 8;
  if (nend > N_NODES) nend = N_NODES;
  float4 acc = make_float4(0.f, 0.f, 0.f, 0.f);
  int curg = -1;
  for (int n = base; n < nend; ++n) {
    int g = batch[n];
    if (g != curg) {
      if (curg >= 0) {
        float* p = &psum[curg * 128 + lane32 * 4];
        atomicAdd(p + 0, acc.x); atomicAdd(p + 1, acc.y);
        atomicAdd(p + 2, acc.z); atomicAdd(p + 3, acc.w);
      }
      acc = make_float4(0.f, 0.f, 0.f, 0.f);
      curg = g;
    }
    float4 v = *(const float4*)&y[(size_t)n * 128 + lane32 * 4];
    acc.x += v.x; acc.y += v.y; acc.z += v.z; acc.w += v.w;
  }
  if (curg >= 0) {
    float* p = &psum[curg * 128 + lane32 * 4];
    atomicAdd(p + 0, acc.x); atomicAdd(p + 1, acc.y);
    atomicAdd(p + 2, acc.z); atomicAdd(p + 3, acc.w);
  }
}

// ---------------- mean + FC + ReLU ----------------
__global__ __launch_bounds__(128) void fc_kernel(
    const float* __restrict__ psum, const int* __restrict__ batch,
    const float* __restrict__ fcW, const float* __restrict__ fcb,
    float* __restrict__ out) {
  __shared__ float pr[128];
  __shared__ int bounds[2];
  int g = blockIdx.x, c = threadIdx.x;
  if (c < 2) {
    int target = g + c;
    int lo = 0, hi = N_NODES;
    while (lo < hi) {
      int mid = (lo + hi) >> 1;
      if (batch[mid] < target) lo = mid + 1; else hi = mid;
    }
    bounds[c] = lo;
  }
  __syncthreads();
  float cnt = (float)(bounds[1] - bounds[0]);
  cnt = cnt > 1.f ? cnt : 1.f;
  pr[c] = psum[g * 128 + c] / cnt;
  __syncthreads();
  float s = fcb[c];
  #pragma unroll 8
  for (int k = 0; k < 128; k++) s += pr[k] * fcW[k * 128 + c];
  out[g * 128 + c] = fmaxf(s, 0.f);
}

extern "C" void kernel_launch(void* const* d_in, const int* in_sizes, int n_in,
                              void* d_out, int out_size, void* d_ws,
                              size_t ws_size, hipStream_t stream) {
  const float* x      = (const float*)d_in[0];
  const int*   ei     = (const int*)d_in[1];
  const int*   batch  = (const int*)d_in[2];
  const float* W1     = (const float*)d_in[3];
  const float* a1_src = (const float*)d_in[4];
  const float* a1_dst = (const float*)d_in[5];
  const float* b1     = (const float*)d_in[6];
  const float* W2     = (const float*)d_in[7];
  const float* a2_src = (const float*)d_in[8];
  const float* a2_dst = (const float*)d_in[9];
  const float* b2     = (const float*)d_in[10];
  const float* fc_W   = (const float*)d_in[11];
  const float* fc_b   = (const float*)d_in[12];
  float* out = (float*)d_out;

  const int* srcp = ei;
  const int* dstp = ei + N_EDGES;
  const int NB = (N_NODES + 255) / 256;  // 196

  // ---- workspace layout ----
  float* x2   = (float*)d_ws;                 // [50000*256]
  float* y    = x2 + (size_t)N_NODES * 256;   // [50000*128]
  float* al1s = y + (size_t)N_NODES * 128;
  float* al1d = al1s + N_NODES * 4;
  float* al2s = al1d + N_NODES * 4;
  float* al2d = al2s + N_NODES;
  float* psum = al2d + N_NODES;               // [64*128]
  us* h1b  = (us*)(psum + N_GRAPHS * 128);    // [50000*256]
  us* h2b  = h1b + (size_t)N_NODES * 256;     // [50000*128]
  us* w1th = h2b + (size_t)N_NODES * 128;
  us* w1tl = w1th + 256 * 128;
  us* w2th = w1tl + 256 * 128;
  us* w2tl = w2th + 128 * 256;
  int* cnt    = (int*)(w2tl + 128 * 256);     // [50000]
  int* bsum   = cnt + N_NODES;
  int* boff   = bsum + 256;
  int* itmp   = boff + 256;
  int* rowst  = itmp + N_NODES;               // [50001]
  int* cursor = rowst + N_NODES + 8;
  int* csrc   = cursor + N_NODES;             // [800000]
  size_t needed = (size_t)((char*)(csrc + N_EDGES) - (char*)d_ws);
  if (ws_size < needed) return;

  hipMemsetAsync(cnt, 0, N_NODES * sizeof(int), stream);
  hipMemsetAsync(psum, 0, N_GRAPHS * 128 * sizeof(float), stream);

  // CSR build
  count_kernel<<<(N_EDGES + 255) / 256, 256, 0, stream>>>(dstp, cnt);
  scan1_kernel<<<NB, 256, 0, stream>>>(cnt, itmp, bsum);
  scan2_kernel<<<1, 256, 0, stream>>>(bsum, boff, NB);
  scan3_kernel<<<NB, 256, 0, stream>>>(cnt, itmp, boff, rowst, cursor);
  scatter_kernel<<<(N_EDGES + 255) / 256, 256, 0, stream>>>(srcp, dstp, cursor, csrc);

  // weight prep
  convW_kernel<<<(2 * 128 * 256 + 255) / 256, 256, 0, stream>>>(
      W1, W2, w1th, w1tl, w2th, w2tl);

  // layer 1
  gemm_bf16x3<<<dim3(391, 2), 256, 0, stream>>>(x, w1th, w1tl, h1b, N_NODES, 256, 128);
  logits1_kernel<<<(N_NODES * 4 + 255) / 256, 256, 0, stream>>>(h1b, a1_src, a1_dst, al1s, al1d);
  agg1_kernel<<<(N_NODES * 64 + 255) / 256, 256, 0, stream>>>(
      h1b, al1s, al1d, rowst, csrc, b1, x2);

  // layer 2
  gemm_bf16x3<<<dim3(391, 1), 256, 0, stream>>>(x2, w2th, w2tl, h2b, N_NODES, 128, 256);
  logits2_kernel<<<(N_NODES + 255) / 256, 256, 0, stream>>>(h2b, a2_src, a2_dst, al2s, al2d);
  agg2_kernel<<<(N_NODES * 64 + 255) / 256, 256, 0, stream>>>(
      h2b, al2s, al2d, rowst, csrc, b2, y);

  // pool + fc
  pool_kernel<<<(N_NODES + PNPB - 1) / PNPB, 256, 0, stream>>>(y, batch, psum);
  fc_kernel<<<N_GRAPHS, 128, 0, stream>>>(psum, batch, fc_W, fc_b, out);
}

// Round 6
// 327.422 us; speedup vs baseline: 1.1634x; 1.0353x over previous
//
#include <hip/hip_runtime.h>
#include <math.h>

#define N_NODES 50000
#define N_EDGES 800000
#define N_GRAPHS 64
#define NEG 0.2f

typedef unsigned short us;
typedef us us2 __attribute__((ext_vector_type(2)));
typedef us us4 __attribute__((ext_vector_type(4)));
typedef us us8 __attribute__((ext_vector_type(8)));
typedef short bf16x8 __attribute__((ext_vector_type(8)));
typedef float f32x4 __attribute__((ext_vector_type(4)));

__device__ __forceinline__ us bf16rn(float f) {
  unsigned int u = __float_as_uint(f);
  u += 0x7FFFu + ((u >> 16) & 1u);
  return (us)(u >> 16);
}
__device__ __forceinline__ float bf2f(us h) {
  return __uint_as_float(((unsigned int)h) << 16);
}
__device__ __forceinline__ float readlane_f(float v, int l) {
  return __uint_as_float((unsigned)__builtin_amdgcn_readlane(__float_as_uint(v), l));
}

// ---------------- split f32 -> bf16 hi/lo (x input) ----------------
__global__ __launch_bounds__(256) void xsplit_kernel(const float* __restrict__ x,
                                                     us* __restrict__ xh,
                                                     us* __restrict__ xl,
                                                     int total4) {
  int i = blockIdx.x * 256 + threadIdx.x;
  if (i >= total4) return;
  float4 v = *(const float4*)&x[(size_t)i * 4];
  us h0 = bf16rn(v.x), h1 = bf16rn(v.y), h2 = bf16rn(v.z), h3 = bf16rn(v.w);
  us4 hv = {h0, h1, h2, h3};
  us4 lv = {bf16rn(v.x - bf2f(h0)), bf16rn(v.y - bf2f(h1)),
            bf16rn(v.z - bf2f(h2)), bf16rn(v.w - bf2f(h3))};
  *(us4*)&xh[(size_t)i * 4] = hv;
  *(us4*)&xl[(size_t)i * 4] = lv;
}

// ---------------- W conversion (both layers in one launch) ----------------
__global__ __launch_bounds__(256) void convW_kernel(
    const float* __restrict__ W1, const float* __restrict__ W2,
    us* __restrict__ w1h, us* __restrict__ w1l,
    us* __restrict__ w2h, us* __restrict__ w2l) {
  int idx = blockIdx.x * 256 + threadIdx.x;
  const float* W; us *oh, *ol; int K, N, li;
  if (idx < 128 * 256) {
    W = W1; oh = w1h; ol = w1l; K = 128; N = 256; li = idx;
  } else if (idx < 2 * 128 * 256) {
    W = W2; oh = w2h; ol = w2l; K = 256; N = 128; li = idx - 128 * 256;
  } else return;
  int n = li / K, k = li - n * K;
  float f = W[(size_t)k * N + n];
  us h = bf16rn(f);
  oh[li] = h;
  ol[li] = bf16rn(f - bf2f(h));
}

// ---------------- MFMA GEMM, bf16x3, pre-split A [M][K] hi/lo ----------------
__global__ __launch_bounds__(256, 2) void gemm_bf16x3(
    const us* __restrict__ Agh, const us* __restrict__ Agl,
    const us* __restrict__ Bth, const us* __restrict__ Btl,
    us* __restrict__ C, int M, int N, int K) {
  __shared__ us Ah[128][40];
  __shared__ us Al[128][40];
  __shared__ us Bh[128][40];
  __shared__ us Bl[128][40];
  int t = threadIdx.x;
  int m0 = blockIdx.x * 128;
  int n0 = blockIdx.y * 128;
  int w = t >> 6, l = t & 63;
  int wr = w >> 1, wc = w & 1;
  int l15 = l & 15, g = l >> 4;

  f32x4 acc[4][4] = {};

  for (int kb = 0; kb < K; kb += 32) {
    us8 z = {};
    #pragma unroll
    for (int i = 0; i < 2; i++) {
      int slot = i * 256 + t;        // 512 slots = 128 rows x 4 kq
      int row = slot >> 2, kq = slot & 3;
      size_t gi = (size_t)(m0 + row) * K + kb + kq * 8;
      bool ok = (m0 + row) < M;
      *(us8*)&Ah[row][kq * 8] = ok ? *(const us8*)&Agh[gi] : z;
      *(us8*)&Al[row][kq * 8] = ok ? *(const us8*)&Agl[gi] : z;
    }
    #pragma unroll
    for (int i = 0; i < 2; i++) {
      int slot = i * 256 + t;
      int n = slot >> 2, kq = slot & 3;
      size_t gi = (size_t)(n0 + n) * K + kb + kq * 8;
      *(us8*)&Bh[n][kq * 8] = *(const us8*)&Bth[gi];
      *(us8*)&Bl[n][kq * 8] = *(const us8*)&Btl[gi];
    }
    __syncthreads();

    bf16x8 af[4], al4[4], bf[4], bl4[4];
    #pragma unroll
    for (int i = 0; i < 4; i++) {
      af[i]  = *(const bf16x8*)&Ah[wr * 64 + i * 16 + l15][g * 8];
      al4[i] = *(const bf16x8*)&Al[wr * 64 + i * 16 + l15][g * 8];
      bf[i]  = *(const bf16x8*)&Bh[wc * 64 + i * 16 + l15][g * 8];
      bl4[i] = *(const bf16x8*)&Bl[wc * 64 + i * 16 + l15][g * 8];
    }
    #pragma unroll
    for (int i = 0; i < 4; i++)
      #pragma unroll
      for (int j = 0; j < 4; j++) {
        acc[i][j] = __builtin_amdgcn_mfma_f32_16x16x32_bf16(af[i], bf[j], acc[i][j], 0, 0, 0);
        acc[i][j] = __builtin_amdgcn_mfma_f32_16x16x32_bf16(af[i], bl4[j], acc[i][j], 0, 0, 0);
        acc[i][j] = __builtin_amdgcn_mfma_f32_16x16x32_bf16(al4[i], bf[j], acc[i][j], 0, 0, 0);
      }
    __syncthreads();
  }

  #pragma unroll
  for (int i = 0; i < 4; i++)
    #pragma unroll
    for (int j = 0; j < 4; j++)
      #pragma unroll
      for (int r = 0; r < 4; r++) {
        int row = m0 + wr * 64 + i * 16 + g * 4 + r;
        if (row < M) {
          int col = n0 + wc * 64 + j * 16 + l15;
          C[(size_t)row * N + col] = bf16rn(acc[i][j][r]);
        }
      }
}

// ---------------- logits layer 1 ----------------
__global__ __launch_bounds__(256) void logits1_kernel(
    const us* __restrict__ h1b, const float* __restrict__ a_src,
    const float* __restrict__ a_dst, float* __restrict__ al_s,
    float* __restrict__ al_d) {
  int idx = blockIdx.x * 256 + threadIdx.x;
  if (idx >= N_NODES * 4) return;
  int n = idx >> 2, h = idx & 3;
  const us* hp = &h1b[(size_t)n * 256 + h * 64];
  float ss = 0.f, sd = 0.f;
  #pragma unroll
  for (int i = 0; i < 8; i++) {
    us8 v = *(const us8*)&hp[i * 8];
    #pragma unroll
    for (int j = 0; j < 8; j++) {
      float f = bf2f(v[j]);
      ss += f * a_src[h * 64 + i * 8 + j];
      sd += f * a_dst[h * 64 + i * 8 + j];
    }
  }
  al_s[idx] = ss;
  al_d[idx] = sd;
}

// ---------------- logits layer 2 ----------------
__global__ __launch_bounds__(256) void logits2_kernel(
    const us* __restrict__ h2b, const float* __restrict__ a_src,
    const float* __restrict__ a_dst, float* __restrict__ al_s,
    float* __restrict__ al_d) {
  int n = blockIdx.x * 256 + threadIdx.x;
  if (n >= N_NODES) return;
  const us* hp = &h2b[(size_t)n * 128];
  float ss = 0.f, sd = 0.f;
  #pragma unroll
  for (int i = 0; i < 16; i++) {
    us8 v = *(const us8*)&hp[i * 8];
    #pragma unroll
    for (int j = 0; j < 8; j++) {
      float f = bf2f(v[j]);
      ss += f * a_src[i * 8 + j];
      sd += f * a_dst[i * 8 + j];
    }
  }
  al_s[n] = ss;
  al_d[n] = sd;
}

// ---------------- CSR build ----------------
__global__ __launch_bounds__(256) void count_kernel(const int* __restrict__ dst,
                                                    int* __restrict__ cnt) {
  int e = blockIdx.x * 256 + threadIdx.x;
  if (e < N_EDGES) atomicAdd(&cnt[dst[e]], 1);
}

__global__ __launch_bounds__(256) void scan1_kernel(const int* __restrict__ cnt,
                                                    int* __restrict__ itmp,
                                                    int* __restrict__ bsum) {
  int i = blockIdx.x * 256 + threadIdx.x;
  int v = (i < N_NODES) ? cnt[i] : 0;
  int lane = threadIdx.x & 63, w = threadIdx.x >> 6;
  int s = v;
  #pragma unroll
  for (int off = 1; off < 64; off <<= 1) {
    int tv = __shfl_up(s, off);
    if (lane >= off) s += tv;
  }
  __shared__ int wsum[4];
  if (lane == 63) wsum[w] = s;
  __syncthreads();
  int add = 0;
  for (int p = 0; p < w; p++) add += wsum[p];
  s += add;
  if (i < N_NODES) itmp[i] = s;
  if (threadIdx.x == 255) bsum[blockIdx.x] = s;
}

__global__ __launch_bounds__(256) void scan2_kernel(const int* __restrict__ bsum,
                                                    int* __restrict__ boff,
                                                    int nb) {
  int t = threadIdx.x;
  int v = (t < nb) ? bsum[t] : 0;
  int lane = t & 63, w = t >> 6;
  int s = v;
  #pragma unroll
  for (int off = 1; off < 64; off <<= 1) {
    int tv = __shfl_up(s, off);
    if (lane >= off) s += tv;
  }
  __shared__ int wsum[4];
  if (lane == 63) wsum[w] = s;
  __syncthreads();
  int add = 0;
  for (int p = 0; p < w; p++) add += wsum[p];
  s += add;
  if (t < nb) boff[t] = s - v;
}

__global__ __launch_bounds__(256) void scan3_kernel(const int* __restrict__ cnt,
                                                    const int* __restrict__ itmp,
                                                    const int* __restrict__ boff,
                                                    int* __restrict__ rowst,
                                                    int* __restrict__ cursor) {
  int i = blockIdx.x * 256 + threadIdx.x;
  if (i < N_NODES) {
    int excl = itmp[i] - cnt[i] + boff[i >> 8];
    rowst[i] = excl;
    cursor[i] = excl;
  }
  if (i == 0) rowst[N_NODES] = N_EDGES;
}

__global__ __launch_bounds__(256) void scatter_kernel(
    const int* __restrict__ src, const int* __restrict__ dst,
    int* __restrict__ cursor, int* __restrict__ csr_src) {
  int e = blockIdx.x * 256 + threadIdx.x;
  if (e < N_EDGES) {
    int p = atomicAdd(&cursor[dst[e]], 1);
    csr_src[p] = src[e];
  }
}

// ---------------- layer-1 aggregation ----------------
// chunk of 16 edges: lane (el + 16h) computes weight of edge el for head h.
// accumulate in batches of 8: scalar row index via readlane, 8 loads in flight.
__global__ __launch_bounds__(256) void agg1_kernel(
    const us* __restrict__ h1b, const float* __restrict__ al_s,
    const float* __restrict__ al_d, const int* __restrict__ rowst,
    const int* __restrict__ csrc, const float* __restrict__ b1,
    us* __restrict__ outh, us* __restrict__ outl) {
  int d = (blockIdx.x * 256 + threadIdx.x) >> 6;
  int lane = threadIdx.x & 63;
  if (d >= N_NODES) return;
  int head = lane >> 4;
  int c0 = lane * 4;
  int wsel = lane & 48;
  float ald = al_d[d * 4 + head];
  float wsum = 0.f, a0 = 0.f, a1 = 0.f, a2 = 0.f, a3 = 0.f;
  {  // self-loop
    float v = al_s[d * 4 + head] + ald;
    v = v > 0.f ? v : NEG * v;
    float w = __expf(v);
    us4 hv = *(const us4*)&h1b[(size_t)d * 256 + c0];
    wsum += w;
    a0 += w * bf2f(hv[0]); a1 += w * bf2f(hv[1]);
    a2 += w * bf2f(hv[2]); a3 += w * bf2f(hv[3]);
  }
  int beg = rowst[d], end = rowst[d + 1];
  int j = beg;
  // full 16-chunks
  for (; j + 16 <= end; j += 16) {
    int el = lane & 15;
    int sv = csrc[j + el];
    float v = al_s[sv * 4 + head] + ald;
    v = v > 0.f ? v : NEG * v;
    float wv = __expf(v);
    #pragma unroll
    for (int half = 0; half < 2; ++half) {
      int ss[8]; us4 hv[8];
      #pragma unroll
      for (int k = 0; k < 8; ++k)
        ss[k] = __builtin_amdgcn_readlane(sv, half * 8 + k);
      #pragma unroll
      for (int k = 0; k < 8; ++k)
        hv[k] = *(const us4*)&h1b[(size_t)(unsigned)ss[k] * 256 + c0];
      #pragma unroll
      for (int k = 0; k < 8; ++k) {
        float w = __shfl(wv, half * 8 + k + wsel);
        wsum += w;
        a0 += w * bf2f(hv[k][0]); a1 += w * bf2f(hv[k][1]);
        a2 += w * bf2f(hv[k][2]); a3 += w * bf2f(hv[k][3]);
      }
    }
  }
  // tail (1..15 edges), batches of 8 zero-padded
  int m = end - j;
  if (m > 0) {
    int el = lane & 15;
    int sv = csrc[j + (el < m ? el : 0)];
    float v = al_s[sv * 4 + head] + ald;
    v = v > 0.f ? v : NEG * v;
    float wv = __expf(v);
    for (int b = 0; b < m; b += 8) {
      int ss[8]; us4 hv[8];
      #pragma unroll
      for (int k = 0; k < 8; ++k) {
        int kk = b + k;
        ss[k] = __builtin_amdgcn_readlane(sv, kk < m ? kk : 0);
      }
      #pragma unroll
      for (int k = 0; k < 8; ++k)
        hv[k] = *(const us4*)&h1b[(size_t)(unsigned)ss[k] * 256 + c0];
      #pragma unroll
      for (int k = 0; k < 8; ++k) {
        int kk = b + k;
        float w = __shfl(wv, (kk < m ? kk : 0) + wsel);
        if (kk >= m) w = 0.f;
        wsum += w;
        a0 += w * bf2f(hv[k][0]); a1 += w * bf2f(hv[k][1]);
        a2 += w * bf2f(hv[k][2]); a3 += w * bf2f(hv[k][3]);
      }
    }
  }
  float inv = 1.f / (wsum + 1e-16f);
  float4 bb = *(const float4*)&b1[c0];
  float o[4] = {a0 * inv + bb.x, a1 * inv + bb.y, a2 * inv + bb.z, a3 * inv + bb.w};
  us4 oh, ol;
  #pragma unroll
  for (int i = 0; i < 4; i++) {
    float e = o[i] > 0.f ? o[i] : expm1f(o[i]);
    us h = bf16rn(e);
    oh[i] = h;
    ol[i] = bf16rn(e - bf2f(h));
  }
  *(us4*)&outh[(size_t)d * 256 + c0] = oh;
  *(us4*)&outl[(size_t)d * 256 + c0] = ol;
}

// ---------------- layer-2 aggregation ----------------
// chunk of 64 edges: lane computes weight of edge lane; accumulate in
// batches of 8 with scalar (readlane) row index AND scalar weight.
__global__ __launch_bounds__(256) void agg2_kernel(
    const us* __restrict__ h2b, const float* __restrict__ al_s,
    const float* __restrict__ al_d, const int* __restrict__ rowst,
    const int* __restrict__ csrc, const float* __restrict__ b2,
    float* __restrict__ out) {
  int d = (blockIdx.x * 256 + threadIdx.x) >> 6;
  int lane = threadIdx.x & 63;
  if (d >= N_NODES) return;
  int c0 = lane * 2;
  float ald = al_d[d];
  float wsum = 0.f, a0 = 0.f, a1 = 0.f;
  {  // self-loop
    float v = al_s[d] + ald;
    v = v > 0.f ? v : NEG * v;
    float w = __expf(v);
    us2 hv = *(const us2*)&h2b[(size_t)d * 128 + c0];
    wsum += w;
    a0 += w * bf2f(hv[0]); a1 += w * bf2f(hv[1]);
  }
  int beg = rowst[d], end = rowst[d + 1];
  for (int j = beg; j < end; j += 64) {
    int m = end - j;
    m = m < 64 ? m : 64;
    int sv = csrc[j + (lane < m ? lane : 0)];
    float v = al_s[sv] + ald;
    v = v > 0.f ? v : NEG * v;
    float wv = __expf(v);
    for (int b = 0; b < m; b += 8) {
      int ss[8]; us2 hv[8];
      #pragma unroll
      for (int k = 0; k < 8; ++k) {
        int kk = b + k;
        ss[k] = __builtin_amdgcn_readlane(sv, kk < m ? kk : 0);
      }
      #pragma unroll
      for (int k = 0; k < 8; ++k)
        hv[k] = *(const us2*)&h2b[(size_t)(unsigned)ss[k] * 128 + c0];
      #pragma unroll
      for (int k = 0; k < 8; ++k) {
        int kk = b + k;
        float w = readlane_f(wv, kk < m ? kk : 0);
        if (kk >= m) w = 0.f;
        wsum += w;
        a0 += w * bf2f(hv[k][0]); a1 += w * bf2f(hv[k][1]);
      }
    }
  }
  float inv = 1.f / (wsum + 1e-16f);
  float2 bb = *(const float2*)&b2[c0];
  float o0 = a0 * inv + bb.x, o1 = a1 * inv + bb.y;
  o0 = o0 > 0.f ? o0 : expm1f(o0);
  o1 = o1 > 0.f ? o1 : expm1f(o1);
  *(float2*)&out[(size_t)d * 128 + c0] = make_float2(o0, o1);
}

// ---------------- pooling ----------------
#define PNPB 128
__global__ __launch_bounds__(256) void pool_kernel(const float* __restrict__ y,
                                                   const int* __restrict__ batch,
                                                   float* __restrict__ psum) {
  int t = threadIdx.x;
  int lane32 = t & 31;
  int sub = t >> 5;
  int base = blockIdx.x * PNPB + sub * (PNPB / 8);
  int nend = base + PNPB / 8;
  if (nend > N_NODES) nend = N_NODES;
  float4 acc = make_float4(0.f, 0.f, 0.f, 0.f);
  int curg = -1;
  for (int n = base; n < nend; ++n) {
    int g = batch[n];
    if (g != curg) {
      if (curg >= 0) {
        float* p = &psum[curg * 128 + lane32 * 4];
        atomicAdd(p + 0, acc.x); atomicAdd(p + 1, acc.y);
        atomicAdd(p + 2, acc.z); atomicAdd(p + 3, acc.w);
      }
      acc = make_float4(0.f, 0.f, 0.f, 0.f);
      curg = g;
    }
    float4 v = *(const float4*)&y[(size_t)n * 128 + lane32 * 4];
    acc.x += v.x; acc.y += v.y; acc.z += v.z; acc.w += v.w;
  }
  if (curg >= 0) {
    float* p = &psum[curg * 128 + lane32 * 4];
    atomicAdd(p + 0, acc.x); atomicAdd(p + 1, acc.y);
    atomicAdd(p + 2, acc.z); atomicAdd(p + 3, acc.w);
  }
}

// ---------------- mean + FC + ReLU ----------------
__global__ __launch_bounds__(128) void fc_kernel(
    const float* __restrict__ psum, const int* __restrict__ batch,
    const float* __restrict__ fcW, const float* __restrict__ fcb,
    float* __restrict__ out) {
  __shared__ float pr[128];
  __shared__ int bounds[2];
  int g = blockIdx.x, c = threadIdx.x;
  if (c < 2) {
    int target = g + c;
    int lo = 0, hi = N_NODES;
    while (lo < hi) {
      int mid = (lo + hi) >> 1;
      if (batch[mid] < target) lo = mid + 1; else hi = mid;
    }
    bounds[c] = lo;
  }
  __syncthreads();
  float cnt = (float)(bounds[1] - bounds[0]);
  cnt = cnt > 1.f ? cnt : 1.f;
  pr[c] = psum[g * 128 + c] / cnt;
  __syncthreads();
  float s = fcb[c];
  #pragma unroll 8
  for (int k = 0; k < 128; k++) s += pr[k] * fcW[k * 128 + c];
  out[g * 128 + c] = fmaxf(s, 0.f);
}

extern "C" void kernel_launch(void* const* d_in, const int* in_sizes, int n_in,
                              void* d_out, int out_size, void* d_ws,
                              size_t ws_size, hipStream_t stream) {
  const float* x      = (const float*)d_in[0];
  const int*   ei     = (const int*)d_in[1];
  const int*   batch  = (const int*)d_in[2];
  const float* W1     = (const float*)d_in[3];
  const float* a1_src = (const float*)d_in[4];
  const float* a1_dst = (const float*)d_in[5];
  const float* b1     = (const float*)d_in[6];
  const float* W2     = (const float*)d_in[7];
  const float* a2_src = (const float*)d_in[8];
  const float* a2_dst = (const float*)d_in[9];
  const float* b2     = (const float*)d_in[10];
  const float* fc_W   = (const float*)d_in[11];
  const float* fc_b   = (const float*)d_in[12];
  float* out = (float*)d_out;

  const int* srcp = ei;
  const int* dstp = ei + N_EDGES;
  const int NB = (N_NODES + 255) / 256;  // 196

  // ---- workspace layout ----
  float* y    = (float*)d_ws;                 // [50000*128]
  float* al1s = y + (size_t)N_NODES * 128;
  float* al1d = al1s + N_NODES * 4;
  float* al2s = al1d + N_NODES * 4;
  float* al2d = al2s + N_NODES;
  float* psum = al2d + N_NODES;               // [64*128]
  us* xh   = (us*)(psum + N_GRAPHS * 128);    // [50000*128]
  us* xl   = xh + (size_t)N_NODES * 128;
  us* x2h  = xl + (size_t)N_NODES * 128;      // [50000*256]
  us* x2l  = x2h + (size_t)N_NODES * 256;
  us* h1b  = x2l + (size_t)N_NODES * 256;     // [50000*256]
  us* h2b  = h1b + (size_t)N_NODES * 256;     // [50000*128]
  us* w1th = h2b + (size_t)N_NODES * 128;
  us* w1tl = w1th + 256 * 128;
  us* w2th = w1tl + 256 * 128;
  us* w2tl = w2th + 128 * 256;
  int* cnt    = (int*)(w2tl + 128 * 256);     // [50000]
  int* bsum   = cnt + N_NODES;
  int* boff   = bsum + 256;
  int* itmp   = boff + 256;
  int* rowst  = itmp + N_NODES;               // [50001]
  int* cursor = rowst + N_NODES + 8;
  int* csrc   = cursor + N_NODES;             // [800000]
  size_t needed = (size_t)((char*)(csrc + N_EDGES) - (char*)d_ws);
  if (ws_size < needed) return;

  hipMemsetAsync(cnt, 0, N_NODES * sizeof(int), stream);
  hipMemsetAsync(psum, 0, N_GRAPHS * 128 * sizeof(float), stream);

  // CSR build
  count_kernel<<<(N_EDGES + 255) / 256, 256, 0, stream>>>(dstp, cnt);
  scan1_kernel<<<NB, 256, 0, stream>>>(cnt, itmp, bsum);
  scan2_kernel<<<1, 256, 0, stream>>>(bsum, boff, NB);
  scan3_kernel<<<NB, 256, 0, stream>>>(cnt, itmp, boff, rowst, cursor);
  scatter_kernel<<<(N_EDGES + 255) / 256, 256, 0, stream>>>(srcp, dstp, cursor, csrc);

  // input prep
  xsplit_kernel<<<(N_NODES * 128 / 4 + 255) / 256, 256, 0, stream>>>(
      x, xh, xl, N_NODES * 128 / 4);
  convW_kernel<<<(2 * 128 * 256 + 255) / 256, 256, 0, stream>>>(
      W1, W2, w1th, w1tl, w2th, w2tl);

  // layer 1
  gemm_bf16x3<<<dim3(391, 2), 256, 0, stream>>>(xh, xl, w1th, w1tl, h1b, N_NODES, 256, 128);
  logits1_kernel<<<(N_NODES * 4 + 255) / 256, 256, 0, stream>>>(h1b, a1_src, a1_dst, al1s, al1d);
  agg1_kernel<<<(N_NODES * 64 + 255) / 256, 256, 0, stream>>>(
      h1b, al1s, al1d, rowst, csrc, b1, x2h, x2l);

  // layer 2
  gemm_bf16x3<<<dim3(391, 1), 256, 0, stream>>>(x2h, x2l, w2th, w2tl, h2b, N_NODES, 128, 256);
  logits2_kernel<<<(N_NODES + 255) / 256, 256, 0, stream>>>(h2b, a2_src, a2_dst, al2s, al2d);
  agg2_kernel<<<(N_NODES * 64 + 255) / 256, 256, 0, stream>>>(
      h2b, al2s, al2d, rowst, csrc, b2, y);

  // pool + fc
  pool_kernel<<<(N_NODES + PNPB - 1) / PNPB, 256, 0, stream>>>(y, batch, psum);
  fc_kernel<<<N_GRAPHS, 128, 0, stream>>>(psum, batch, fc_W, fc_b, out);
}

// Round 7
// 313.465 us; speedup vs baseline: 1.2152x; 1.0445x over previous
//
#include <hip/hip_runtime.h>
#include <math.h>

#define N_NODES 50000
#define N_EDGES 800000
#define N_GRAPHS 64
#define NEG 0.2f

typedef unsigned short us;
typedef us us2 __attribute__((ext_vector_type(2)));
typedef us us4 __attribute__((ext_vector_type(4)));
typedef us us8 __attribute__((ext_vector_type(8)));
typedef short bf16x8 __attribute__((ext_vector_type(8)));
typedef float f32x4 __attribute__((ext_vector_type(4)));

__device__ __forceinline__ us bf16rn(float f) {
  unsigned int u = __float_as_uint(f);
  u += 0x7FFFu + ((u >> 16) & 1u);
  return (us)(u >> 16);
}
__device__ __forceinline__ float bf2f(us h) {
  return __uint_as_float(((unsigned int)h) << 16);
}
__device__ __forceinline__ float readlane_f(float v, int l) {
  return __uint_as_float((unsigned)__builtin_amdgcn_readlane(__float_as_uint(v), l));
}

// ---------------- init: zero cnt + psum in one launch ----------------
__global__ __launch_bounds__(256) void init_kernel(int* __restrict__ cnt,
                                                   float* __restrict__ psum) {
  int i = blockIdx.x * 256 + threadIdx.x;
  if (i < N_NODES) cnt[i] = 0;
  if (i < N_GRAPHS * 128) psum[i] = 0.f;
}

// ---------------- split f32 -> bf16 hi/lo (x input) ----------------
__global__ __launch_bounds__(256) void xsplit_kernel(const float* __restrict__ x,
                                                     us* __restrict__ xh,
                                                     us* __restrict__ xl,
                                                     int total4) {
  int i = blockIdx.x * 256 + threadIdx.x;
  if (i >= total4) return;
  float4 v = *(const float4*)&x[(size_t)i * 4];
  us h0 = bf16rn(v.x), h1 = bf16rn(v.y), h2 = bf16rn(v.z), h3 = bf16rn(v.w);
  us4 hv = {h0, h1, h2, h3};
  us4 lv = {bf16rn(v.x - bf2f(h0)), bf16rn(v.y - bf2f(h1)),
            bf16rn(v.z - bf2f(h2)), bf16rn(v.w - bf2f(h3))};
  *(us4*)&xh[(size_t)i * 4] = hv;
  *(us4*)&xl[(size_t)i * 4] = lv;
}

// ---------------- W conversion (both layers in one launch) ----------------
__global__ __launch_bounds__(256) void convW_kernel(
    const float* __restrict__ W1, const float* __restrict__ W2,
    us* __restrict__ w1h, us* __restrict__ w1l,
    us* __restrict__ w2h, us* __restrict__ w2l) {
  int idx = blockIdx.x * 256 + threadIdx.x;
  const float* W; us *oh, *ol; int K, N, li;
  if (idx < 128 * 256) {
    W = W1; oh = w1h; ol = w1l; K = 128; N = 256; li = idx;
  } else if (idx < 2 * 128 * 256) {
    W = W2; oh = w2h; ol = w2l; K = 256; N = 128; li = idx - 128 * 256;
  } else return;
  int n = li / K, k = li - n * K;
  float f = W[(size_t)k * N + n];
  us h = bf16rn(f);
  oh[li] = h;
  ol[li] = bf16rn(f - bf2f(h));
}

// ---------------- MFMA GEMM, bf16x3, pre-split A [M][K] hi/lo ----------------
// epilogue: C tile staged in LDS, written as us8 coalesced stores
__global__ __launch_bounds__(256, 2) void gemm_bf16x3(
    const us* __restrict__ Agh, const us* __restrict__ Agl,
    const us* __restrict__ Bth, const us* __restrict__ Btl,
    us* __restrict__ C, int M, int N, int K) {
  __shared__ us smem[4][128][40];
  int t = threadIdx.x;
  int m0 = blockIdx.x * 128;
  int n0 = blockIdx.y * 128;
  int w = t >> 6, l = t & 63;
  int wr = w >> 1, wc = w & 1;
  int l15 = l & 15, g = l >> 4;

  f32x4 acc[4][4] = {};

  for (int kb = 0; kb < K; kb += 32) {
    us8 z = {};
    #pragma unroll
    for (int i = 0; i < 2; i++) {
      int slot = i * 256 + t;        // 512 slots = 128 rows x 4 kq
      int row = slot >> 2, kq = slot & 3;
      size_t gi = (size_t)(m0 + row) * K + kb + kq * 8;
      bool ok = (m0 + row) < M;
      *(us8*)&smem[0][row][kq * 8] = ok ? *(const us8*)&Agh[gi] : z;
      *(us8*)&smem[1][row][kq * 8] = ok ? *(const us8*)&Agl[gi] : z;
    }
    #pragma unroll
    for (int i = 0; i < 2; i++) {
      int slot = i * 256 + t;
      int n = slot >> 2, kq = slot & 3;
      size_t gi = (size_t)(n0 + n) * K + kb + kq * 8;
      *(us8*)&smem[2][n][kq * 8] = *(const us8*)&Bth[gi];
      *(us8*)&smem[3][n][kq * 8] = *(const us8*)&Btl[gi];
    }
    __syncthreads();

    bf16x8 af[4], al4[4], bf[4], bl4[4];
    #pragma unroll
    for (int i = 0; i < 4; i++) {
      af[i]  = *(const bf16x8*)&smem[0][wr * 64 + i * 16 + l15][g * 8];
      al4[i] = *(const bf16x8*)&smem[1][wr * 64 + i * 16 + l15][g * 8];
      bf[i]  = *(const bf16x8*)&smem[2][wc * 64 + i * 16 + l15][g * 8];
      bl4[i] = *(const bf16x8*)&smem[3][wc * 64 + i * 16 + l15][g * 8];
    }
    #pragma unroll
    for (int i = 0; i < 4; i++)
      #pragma unroll
      for (int j = 0; j < 4; j++) {
        acc[i][j] = __builtin_amdgcn_mfma_f32_16x16x32_bf16(af[i], bf[j], acc[i][j], 0, 0, 0);
        acc[i][j] = __builtin_amdgcn_mfma_f32_16x16x32_bf16(af[i], bl4[j], acc[i][j], 0, 0, 0);
        acc[i][j] = __builtin_amdgcn_mfma_f32_16x16x32_bf16(al4[i], bf[j], acc[i][j], 0, 0, 0);
      }
    __syncthreads();
  }

  // stage C tile in LDS (overlaying the staging buffers), then us8 stores
  us* ct = &smem[0][0][0];  // 128*128 us = 32 KB <= 40 KB
  #pragma unroll
  for (int i = 0; i < 4; i++)
    #pragma unroll
    for (int j = 0; j < 4; j++)
      #pragma unroll
      for (int r = 0; r < 4; r++) {
        int row = wr * 64 + i * 16 + g * 4 + r;
        int col = wc * 64 + j * 16 + l15;
        ct[row * 128 + col] = bf16rn(acc[i][j][r]);
      }
  __syncthreads();
  #pragma unroll
  for (int q = 0; q < 8; q++) {
    int slot = q * 256 + t;           // 2048 slots = 128 rows x 16 col8
    int row = slot >> 4, col8 = slot & 15;
    if (m0 + row < M) {
      us8 v = *(const us8*)&ct[row * 128 + col8 * 8];
      *(us8*)&C[(size_t)(m0 + row) * N + n0 + col8 * 8] = v;
    }
  }
}

// ---------------- logits layer 1 ----------------
__global__ __launch_bounds__(256) void logits1_kernel(
    const us* __restrict__ h1b, const float* __restrict__ a_src,
    const float* __restrict__ a_dst, float* __restrict__ al_s,
    float* __restrict__ al_d) {
  int idx = blockIdx.x * 256 + threadIdx.x;
  if (idx >= N_NODES * 4) return;
  int n = idx >> 2, h = idx & 3;
  const us* hp = &h1b[(size_t)n * 256 + h * 64];
  float ss = 0.f, sd = 0.f;
  #pragma unroll
  for (int i = 0; i < 8; i++) {
    us8 v = *(const us8*)&hp[i * 8];
    #pragma unroll
    for (int j = 0; j < 8; j++) {
      float f = bf2f(v[j]);
      ss += f * a_src[h * 64 + i * 8 + j];
      sd += f * a_dst[h * 64 + i * 8 + j];
    }
  }
  al_s[idx] = ss;
  al_d[idx] = sd;
}

// ---------------- logits layer 2 ----------------
__global__ __launch_bounds__(256) void logits2_kernel(
    const us* __restrict__ h2b, const float* __restrict__ a_src,
    const float* __restrict__ a_dst, float* __restrict__ al_s,
    float* __restrict__ al_d) {
  int n = blockIdx.x * 256 + threadIdx.x;
  if (n >= N_NODES) return;
  const us* hp = &h2b[(size_t)n * 128];
  float ss = 0.f, sd = 0.f;
  #pragma unroll
  for (int i = 0; i < 16; i++) {
    us8 v = *(const us8*)&hp[i * 8];
    #pragma unroll
    for (int j = 0; j < 8; j++) {
      float f = bf2f(v[j]);
      ss += f * a_src[i * 8 + j];
      sd += f * a_dst[i * 8 + j];
    }
  }
  al_s[n] = ss;
  al_d[n] = sd;
}

// ---------------- CSR build ----------------
__global__ __launch_bounds__(256) void count_kernel(const int* __restrict__ dst,
                                                    int* __restrict__ cnt) {
  int e = blockIdx.x * 256 + threadIdx.x;
  if (e < N_EDGES) atomicAdd(&cnt[dst[e]], 1);
}

__global__ __launch_bounds__(256) void scan1_kernel(const int* __restrict__ cnt,
                                                    int* __restrict__ itmp,
                                                    int* __restrict__ bsum) {
  int i = blockIdx.x * 256 + threadIdx.x;
  int v = (i < N_NODES) ? cnt[i] : 0;
  int lane = threadIdx.x & 63, w = threadIdx.x >> 6;
  int s = v;
  #pragma unroll
  for (int off = 1; off < 64; off <<= 1) {
    int tv = __shfl_up(s, off);
    if (lane >= off) s += tv;
  }
  __shared__ int wsum[4];
  if (lane == 63) wsum[w] = s;
  __syncthreads();
  int add = 0;
  for (int p = 0; p < w; p++) add += wsum[p];
  s += add;
  if (i < N_NODES) itmp[i] = s;
  if (threadIdx.x == 255) bsum[blockIdx.x] = s;
}

__global__ __launch_bounds__(256) void scan2_kernel(const int* __restrict__ bsum,
                                                    int* __restrict__ boff,
                                                    int nb) {
  int t = threadIdx.x;
  int v = (t < nb) ? bsum[t] : 0;
  int lane = t & 63, w = t >> 6;
  int s = v;
  #pragma unroll
  for (int off = 1; off < 64; off <<= 1) {
    int tv = __shfl_up(s, off);
    if (lane >= off) s += tv;
  }
  __shared__ int wsum[4];
  if (lane == 63) wsum[w] = s;
  __syncthreads();
  int add = 0;
  for (int p = 0; p < w; p++) add += wsum[p];
  s += add;
  if (t < nb) boff[t] = s - v;
}

__global__ __launch_bounds__(256) void scan3_kernel(const int* __restrict__ cnt,
                                                    const int* __restrict__ itmp,
                                                    const int* __restrict__ boff,
                                                    int* __restrict__ rowst,
                                                    int* __restrict__ cursor) {
  int i = blockIdx.x * 256 + threadIdx.x;
  if (i < N_NODES) {
    int excl = itmp[i] - cnt[i] + boff[i >> 8];
    rowst[i] = excl;
    cursor[i] = excl;
  }
  if (i == 0) rowst[N_NODES] = N_EDGES;
}

__global__ __launch_bounds__(256) void scatter_kernel(
    const int* __restrict__ src, const int* __restrict__ dst,
    int* __restrict__ cursor, int* __restrict__ csr_src) {
  int e = blockIdx.x * 256 + threadIdx.x;
  if (e < N_EDGES) {
    int p = atomicAdd(&cursor[dst[e]], 1);
    csr_src[p] = src[e];
  }
}

// ---------------- layer-1 aggregation: batch-4 readlane gathers ----------------
__global__ __launch_bounds__(256) void agg1_kernel(
    const us* __restrict__ h1b, const float* __restrict__ al_s,
    const float* __restrict__ al_d, const int* __restrict__ rowst,
    const int* __restrict__ csrc, const float* __restrict__ b1,
    us* __restrict__ outh, us* __restrict__ outl) {
  int d = (blockIdx.x * 256 + threadIdx.x) >> 6;
  int lane = threadIdx.x & 63;
  if (d >= N_NODES) return;
  int head = lane >> 4;
  int c0 = lane * 4;
  int wsel = lane & 48;
  float ald = al_d[d * 4 + head];
  float wsum = 0.f, a0 = 0.f, a1 = 0.f, a2 = 0.f, a3 = 0.f;
  {  // self-loop
    float v = al_s[d * 4 + head] + ald;
    v = v > 0.f ? v : NEG * v;
    float w = __expf(v);
    us4 hv = *(const us4*)&h1b[(size_t)d * 256 + c0];
    wsum += w;
    a0 += w * bf2f(hv[0]); a1 += w * bf2f(hv[1]);
    a2 += w * bf2f(hv[2]); a3 += w * bf2f(hv[3]);
  }
  int beg = rowst[d], end = rowst[d + 1];
  int j = beg;
  for (; j + 16 <= end; j += 16) {
    int el = lane & 15;
    int sv = csrc[j + el];
    float v = al_s[sv * 4 + head] + ald;
    v = v > 0.f ? v : NEG * v;
    float wv = __expf(v);
    #pragma unroll
    for (int q = 0; q < 16; q += 4) {
      int s0 = __builtin_amdgcn_readlane(sv, q + 0);
      int s1 = __builtin_amdgcn_readlane(sv, q + 1);
      int s2 = __builtin_amdgcn_readlane(sv, q + 2);
      int s3 = __builtin_amdgcn_readlane(sv, q + 3);
      us4 h0 = *(const us4*)&h1b[(size_t)(unsigned)s0 * 256 + c0];
      us4 h1 = *(const us4*)&h1b[(size_t)(unsigned)s1 * 256 + c0];
      us4 h2 = *(const us4*)&h1b[(size_t)(unsigned)s2 * 256 + c0];
      us4 h3 = *(const us4*)&h1b[(size_t)(unsigned)s3 * 256 + c0];
      float w0 = __shfl(wv, q + 0 + wsel);
      float w1 = __shfl(wv, q + 1 + wsel);
      float w2 = __shfl(wv, q + 2 + wsel);
      float w3 = __shfl(wv, q + 3 + wsel);
      wsum += w0 + w1 + w2 + w3;
      a0 += w0 * bf2f(h0[0]) + w1 * bf2f(h1[0]) + w2 * bf2f(h2[0]) + w3 * bf2f(h3[0]);
      a1 += w0 * bf2f(h0[1]) + w1 * bf2f(h1[1]) + w2 * bf2f(h2[1]) + w3 * bf2f(h3[1]);
      a2 += w0 * bf2f(h0[2]) + w1 * bf2f(h1[2]) + w2 * bf2f(h2[2]) + w3 * bf2f(h3[2]);
      a3 += w0 * bf2f(h0[3]) + w1 * bf2f(h1[3]) + w2 * bf2f(h2[3]) + w3 * bf2f(h3[3]);
    }
  }
  int m = end - j;
  if (m > 0) {
    int el = lane & 15;
    int sv = csrc[j + (el < m ? el : 0)];
    float v = al_s[sv * 4 + head] + ald;
    v = v > 0.f ? v : NEG * v;
    float wv = __expf(v);
    for (int q = 0; q < m; q += 4) {
      int k0 = q, k1 = q + 1 < m ? q + 1 : 0, k2 = q + 2 < m ? q + 2 : 0,
          k3 = q + 3 < m ? q + 3 : 0;
      int s0 = __builtin_amdgcn_readlane(sv, k0);
      int s1 = __builtin_amdgcn_readlane(sv, k1);
      int s2 = __builtin_amdgcn_readlane(sv, k2);
      int s3 = __builtin_amdgcn_readlane(sv, k3);
      us4 h0 = *(const us4*)&h1b[(size_t)(unsigned)s0 * 256 + c0];
      us4 h1 = *(const us4*)&h1b[(size_t)(unsigned)s1 * 256 + c0];
      us4 h2 = *(const us4*)&h1b[(size_t)(unsigned)s2 * 256 + c0];
      us4 h3 = *(const us4*)&h1b[(size_t)(unsigned)s3 * 256 + c0];
      float w0 = __shfl(wv, k0 + wsel);
      float w1 = __shfl(wv, k1 + wsel);
      float w2 = __shfl(wv, k2 + wsel);
      float w3 = __shfl(wv, k3 + wsel);
      if (q + 1 >= m) w1 = 0.f;
      if (q + 2 >= m) w2 = 0.f;
      if (q + 3 >= m) w3 = 0.f;
      wsum += w0 + w1 + w2 + w3;
      a0 += w0 * bf2f(h0[0]) + w1 * bf2f(h1[0]) + w2 * bf2f(h2[0]) + w3 * bf2f(h3[0]);
      a1 += w0 * bf2f(h0[1]) + w1 * bf2f(h1[1]) + w2 * bf2f(h2[1]) + w3 * bf2f(h3[1]);
      a2 += w0 * bf2f(h0[2]) + w1 * bf2f(h1[2]) + w2 * bf2f(h2[2]) + w3 * bf2f(h3[2]);
      a3 += w0 * bf2f(h0[3]) + w1 * bf2f(h1[3]) + w2 * bf2f(h2[3]) + w3 * bf2f(h3[3]);
    }
  }
  float inv = 1.f / (wsum + 1e-16f);
  float4 bb = *(const float4*)&b1[c0];
  float o[4] = {a0 * inv + bb.x, a1 * inv + bb.y, a2 * inv + bb.z, a3 * inv + bb.w};
  us4 oh, ol;
  #pragma unroll
  for (int i = 0; i < 4; i++) {
    float e = o[i] > 0.f ? o[i] : expm1f(o[i]);
    us h = bf16rn(e);
    oh[i] = h;
    ol[i] = bf16rn(e - bf2f(h));
  }
  *(us4*)&outh[(size_t)d * 256 + c0] = oh;
  *(us4*)&outl[(size_t)d * 256 + c0] = ol;
}

// ---------------- layer-2 aggregation: batch-4 readlane gathers ----------------
__global__ __launch_bounds__(256) void agg2_kernel(
    const us* __restrict__ h2b, const float* __restrict__ al_s,
    const float* __restrict__ al_d, const int* __restrict__ rowst,
    const int* __restrict__ csrc, const float* __restrict__ b2,
    float* __restrict__ out) {
  int d = (blockIdx.x * 256 + threadIdx.x) >> 6;
  int lane = threadIdx.x & 63;
  if (d >= N_NODES) return;
  int c0 = lane * 2;
  float ald = al_d[d];
  float wsum = 0.f, a0 = 0.f, a1 = 0.f;
  {  // self-loop
    float v = al_s[d] + ald;
    v = v > 0.f ? v : NEG * v;
    float w = __expf(v);
    us2 hv = *(const us2*)&h2b[(size_t)d * 128 + c0];
    wsum += w;
    a0 += w * bf2f(hv[0]); a1 += w * bf2f(hv[1]);
  }
  int beg = rowst[d], end = rowst[d + 1];
  int j = beg;
  for (; j + 64 <= end; j += 64) {
    int sv = csrc[j + lane];
    float v = al_s[sv] + ald;
    v = v > 0.f ? v : NEG * v;
    float wv = __expf(v);
    for (int q = 0; q < 64; q += 4) {
      int s0 = __builtin_amdgcn_readlane(sv, q + 0);
      int s1 = __builtin_amdgcn_readlane(sv, q + 1);
      int s2 = __builtin_amdgcn_readlane(sv, q + 2);
      int s3 = __builtin_amdgcn_readlane(sv, q + 3);
      us2 h0 = *(const us2*)&h2b[(size_t)(unsigned)s0 * 128 + c0];
      us2 h1 = *(const us2*)&h2b[(size_t)(unsigned)s1 * 128 + c0];
      us2 h2 = *(const us2*)&h2b[(size_t)(unsigned)s2 * 128 + c0];
      us2 h3 = *(const us2*)&h2b[(size_t)(unsigned)s3 * 128 + c0];
      float w0 = readlane_f(wv, q + 0);
      float w1 = readlane_f(wv, q + 1);
      float w2 = readlane_f(wv, q + 2);
      float w3 = readlane_f(wv, q + 3);
      wsum += w0 + w1 + w2 + w3;
      a0 += w0 * bf2f(h0[0]) + w1 * bf2f(h1[0]) + w2 * bf2f(h2[0]) + w3 * bf2f(h3[0]);
      a1 += w0 * bf2f(h0[1]) + w1 * bf2f(h1[1]) + w2 * bf2f(h2[1]) + w3 * bf2f(h3[1]);
    }
  }
  int m = end - j;
  if (m > 0) {
    int sv = csrc[j + (lane < m ? lane : 0)];
    float v = al_s[sv] + ald;
    v = v > 0.f ? v : NEG * v;
    float wv = __expf(v);
    for (int q = 0; q < m; q += 4) {
      int k0 = q, k1 = q + 1 < m ? q + 1 : 0, k2 = q + 2 < m ? q + 2 : 0,
          k3 = q + 3 < m ? q + 3 : 0;
      int s0 = __builtin_amdgcn_readlane(sv, k0);
      int s1 = __builtin_amdgcn_readlane(sv, k1);
      int s2 = __builtin_amdgcn_readlane(sv, k2);
      int s3 = __builtin_amdgcn_readlane(sv, k3);
      us2 h0 = *(const us2*)&h2b[(size_t)(unsigned)s0 * 128 + c0];
      us2 h1 = *(const us2*)&h2b[(size_t)(unsigned)s1 * 128 + c0];
      us2 h2 = *(const us2*)&h2b[(size_t)(unsigned)s2 * 128 + c0];
      us2 h3 = *(const us2*)&h2b[(size_t)(unsigned)s3 * 128 + c0];
      float w0 = readlane_f(wv, k0);
      float w1 = readlane_f(wv, k1);
      float w2 = readlane_f(wv, k2);
      float w3 = readlane_f(wv, k3);
      if (q + 1 >= m) w1 = 0.f;
      if (q + 2 >= m) w2 = 0.f;
      if (q + 3 >= m) w3 = 0.f;
      wsum += w0 + w1 + w2 + w3;
      a0 += w0 * bf2f(h0[0]) + w1 * bf2f(h1[0]) + w2 * bf2f(h2[0]) + w3 * bf2f(h3[0]);
      a1 += w0 * bf2f(h0[1]) + w1 * bf2f(h1[1]) + w2 * bf2f(h2[1]) + w3 * bf2f(h3[1]);
    }
  }
  float inv = 1.f / (wsum + 1e-16f);
  float2 bb = *(const float2*)&b2[c0];
  float o0 = a0 * inv + bb.x, o1 = a1 * inv + bb.y;
  o0 = o0 > 0.f ? o0 : expm1f(o0);
  o1 = o1 > 0.f ? o1 : expm1f(o1);
  *(float2*)&out[(size_t)d * 128 + c0] = make_float2(o0, o1);
}

// ---------------- pooling ----------------
#define PNPB 128
__global__ __launch_bounds__(256) void pool_kernel(const float* __restrict__ y,
                                                   const int* __restrict__ batch,
                                                   float* __restrict__ psum) {
  int t = threadIdx.x;
  int lane32 = t & 31;
  int sub = t >> 5;
  int base = blockIdx.x * PNPB + sub * (PNPB / 8);
  int nend = base + PNPB / 8;
  if (nend > N_NODES) nend = N_NODES;
  float4 acc = make_float4(0.f, 0.f, 0.f, 0.f);
  int curg = -1;
  for (int n = base; n < nend; ++n) {
    int g = batch[n];
    if (g != curg) {
      if (curg >= 0) {
        float* p = &psum[curg * 128 + lane32 * 4];
        atomicAdd(p + 0, acc.x); atomicAdd(p + 1, acc.y);
        atomicAdd(p + 2, acc.z); atomicAdd(p + 3, acc.w);
      }
      acc = make_float4(0.f, 0.f, 0.f, 0.f);
      curg = g;
    }
    float4 v = *(const float4*)&y[(size_t)n * 128 + lane32 * 4];
    acc.x += v.x; acc.y += v.y; acc.z += v.z; acc.w += v.w;
  }
  if (curg >= 0) {
    float* p = &psum[curg * 128 + lane32 * 4];
    atomicAdd(p + 0, acc.x); atomicAdd(p + 1, acc.y);
    atomicAdd(p + 2, acc.z); atomicAdd(p + 3, acc.w);
  }
}

// ---------------- mean + FC + ReLU ----------------
__global__ __launch_bounds__(128) void fc_kernel(
    const float* __restrict__ psum, const int* __restrict__ batch,
    const float* __restrict__ fcW, const float* __restrict__ fcb,
    float* __restrict__ out) {
  __shared__ float pr[128];
  __shared__ int bounds[2];
  int g = blockIdx.x, c = threadIdx.x;
  if (c < 2) {
    int target = g + c;
    int lo = 0, hi = N_NODES;
    while (lo < hi) {
      int mid = (lo + hi) >> 1;
      if (batch[mid] < target) lo = mid + 1; else hi = mid;
    }
    bounds[c] = lo;
  }
  __syncthreads();
  float cnt = (float)(bounds[1] - bounds[0]);
  cnt = cnt > 1.f ? cnt : 1.f;
  pr[c] = psum[g * 128 + c] / cnt;
  __syncthreads();
  float s = fcb[c];
  #pragma unroll 8
  for (int k = 0; k < 128; k++) s += pr[k] * fcW[k * 128 + c];
  out[g * 128 + c] = fmaxf(s, 0.f);
}

extern "C" void kernel_launch(void* const* d_in, const int* in_sizes, int n_in,
                              void* d_out, int out_size, void* d_ws,
                              size_t ws_size, hipStream_t stream) {
  const float* x      = (const float*)d_in[0];
  const int*   ei     = (const int*)d_in[1];
  const int*   batch  = (const int*)d_in[2];
  const float* W1     = (const float*)d_in[3];
  const float* a1_src = (const float*)d_in[4];
  const float* a1_dst = (const float*)d_in[5];
  const float* b1     = (const float*)d_in[6];
  const float* W2     = (const float*)d_in[7];
  const float* a2_src = (const float*)d_in[8];
  const float* a2_dst = (const float*)d_in[9];
  const float* b2     = (const float*)d_in[10];
  const float* fc_W   = (const float*)d_in[11];
  const float* fc_b   = (const float*)d_in[12];
  float* out = (float*)d_out;

  const int* srcp = ei;
  const int* dstp = ei + N_EDGES;
  const int NB = (N_NODES + 255) / 256;  // 196

  // ---- workspace layout ----
  float* y    = (float*)d_ws;                 // [50000*128]
  float* al1s = y + (size_t)N_NODES * 128;
  float* al1d = al1s + N_NODES * 4;
  float* al2s = al1d + N_NODES * 4;
  float* al2d = al2s + N_NODES;
  float* psum = al2d + N_NODES;               // [64*128]
  us* xh   = (us*)(psum + N_GRAPHS * 128);    // [50000*128]
  us* xl   = xh + (size_t)N_NODES * 128;
  us* x2h  = xl + (size_t)N_NODES * 128;      // [50000*256]
  us* x2l  = x2h + (size_t)N_NODES * 256;
  us* h1b  = x2l + (size_t)N_NODES * 256;     // [50000*256]
  us* h2b  = h1b + (size_t)N_NODES * 256;     // [50000*128]
  us* w1th = h2b + (size_t)N_NODES * 128;
  us* w1tl = w1th + 256 * 128;
  us* w2th = w1tl + 256 * 128;
  us* w2tl = w2th + 128 * 256;
  int* cnt    = (int*)(w2tl + 128 * 256);     // [50000]
  int* bsum   = cnt + N_NODES;
  int* boff   = bsum + 256;
  int* itmp   = boff + 256;
  int* rowst  = itmp + N_NODES;               // [50001]
  int* cursor = rowst + N_NODES + 8;
  int* csrc   = cursor + N_NODES;             // [800000]
  size_t needed = (size_t)((char*)(csrc + N_EDGES) - (char*)d_ws);
  if (ws_size < needed) return;

  init_kernel<<<NB, 256, 0, stream>>>(cnt, psum);

  // CSR build
  count_kernel<<<(N_EDGES + 255) / 256, 256, 0, stream>>>(dstp, cnt);
  scan1_kernel<<<NB, 256, 0, stream>>>(cnt, itmp, bsum);
  scan2_kernel<<<1, 256, 0, stream>>>(bsum, boff, NB);
  scan3_kernel<<<NB, 256, 0, stream>>>(cnt, itmp, boff, rowst, cursor);
  scatter_kernel<<<(N_EDGES + 255) / 256, 256, 0, stream>>>(srcp, dstp, cursor, csrc);

  // input prep
  xsplit_kernel<<<(N_NODES * 128 / 4 + 255) / 256, 256, 0, stream>>>(
      x, xh, xl, N_NODES * 128 / 4);
  convW_kernel<<<(2 * 128 * 256 + 255) / 256, 256, 0, stream>>>(
      W1, W2, w1th, w1tl, w2th, w2tl);

  // layer 1
  gemm_bf16x3<<<dim3(391, 2), 256, 0, stream>>>(xh, xl, w1th, w1tl, h1b, N_NODES, 256, 128);
  logits1_kernel<<<(N_NODES * 4 + 255) / 256, 256, 0, stream>>>(h1b, a1_src, a1_dst, al1s, al1d);
  agg1_kernel<<<(N_NODES * 64 + 255) / 256, 256, 0, stream>>>(
      h1b, al1s, al1d, rowst, csrc, b1, x2h, x2l);

  // layer 2
  gemm_bf16x3<<<dim3(391, 1), 256, 0, stream>>>(x2h, x2l, w2th, w2tl, h2b, N_NODES, 128, 256);
  logits2_kernel<<<(N_NODES + 255) / 256, 256, 0, stream>>>(h2b, a2_src, a2_dst, al2s, al2d);
  agg2_kernel<<<(N_NODES * 64 + 255) / 256, 256, 0, stream>>>(
      h2b, al2s, al2d, rowst, csrc, b2, y);

  // pool + fc
  pool_kernel<<<(N_NODES + PNPB - 1) / PNPB, 256, 0, stream>>>(y, batch, psum);
  fc_kernel<<<N_GRAPHS, 128, 0, stream>>>(psum, batch, fc_W, fc_b, out);
}

// Round 8
// 281.851 us; speedup vs baseline: 1.3515x; 1.1122x over previous
//
#include <hip/hip_runtime.h>
#include <math.h>

#define N_NODES 50000
#define N_EDGES 800000
#define N_GRAPHS 64
#define NEG 0.2f

typedef unsigned short us;
typedef us us2 __attribute__((ext_vector_type(2)));
typedef us us4 __attribute__((ext_vector_type(4)));
typedef us us8 __attribute__((ext_vector_type(8)));
typedef short bf16x8 __attribute__((ext_vector_type(8)));
typedef float f32x4 __attribute__((ext_vector_type(4)));

__device__ __forceinline__ us bf16rn(float f) {
  unsigned int u = __float_as_uint(f);
  u += 0x7FFFu + ((u >> 16) & 1u);
  return (us)(u >> 16);
}
__device__ __forceinline__ float bf2f(us h) {
  return __uint_as_float(((unsigned int)h) << 16);
}
__device__ __forceinline__ float readlane_f(float v, int l) {
  return __uint_as_float((unsigned)__builtin_amdgcn_readlane(__float_as_uint(v), l));
}

// ---------------- prep: xsplit + convW + zero-init, one launch ----------------
// blocks [0,6250): xsplit; [6250,6506): convW; [6506,6702): init
__global__ __launch_bounds__(256) void prep_kernel(
    const float* __restrict__ x, us* __restrict__ xh, us* __restrict__ xl,
    const float* __restrict__ W1, const float* __restrict__ W2,
    us* __restrict__ w1h, us* __restrict__ w1l,
    us* __restrict__ w2h, us* __restrict__ w2l,
    int* __restrict__ cnt, float* __restrict__ psum) {
  int bid = blockIdx.x, t = threadIdx.x;
  if (bid < 6250) {
    int i = bid * 256 + t;  // < 1.6M
    float4 v = *(const float4*)&x[(size_t)i * 4];
    us h0 = bf16rn(v.x), h1 = bf16rn(v.y), h2 = bf16rn(v.z), h3 = bf16rn(v.w);
    us4 hv = {h0, h1, h2, h3};
    us4 lv = {bf16rn(v.x - bf2f(h0)), bf16rn(v.y - bf2f(h1)),
              bf16rn(v.z - bf2f(h2)), bf16rn(v.w - bf2f(h3))};
    *(us4*)&xh[(size_t)i * 4] = hv;
    *(us4*)&xl[(size_t)i * 4] = lv;
  } else if (bid < 6506) {
    int idx = (bid - 6250) * 256 + t;  // < 65536
    const float* W; us *oh, *ol; int K, N, li;
    if (idx < 128 * 256) { W = W1; oh = w1h; ol = w1l; K = 128; N = 256; li = idx; }
    else { W = W2; oh = w2h; ol = w2l; K = 256; N = 128; li = idx - 128 * 256; }
    int n = li / K, k = li - n * K;
    float f = W[(size_t)k * N + n];
    us h = bf16rn(f);
    oh[li] = h;
    ol[li] = bf16rn(f - bf2f(h));
  } else {
    int i = (bid - 6506) * 256 + t;
    if (i < N_NODES) cnt[i] = 0;
    if (i < N_GRAPHS * 128) psum[i] = 0.f;
  }
}

// ---------------- MFMA GEMM, bf16x3, pre-split A; fused logits epilogue ----------------
__global__ __launch_bounds__(256, 2) void gemm_bf16x3(
    const us* __restrict__ Agh, const us* __restrict__ Agl,
    const us* __restrict__ Bth, const us* __restrict__ Btl,
    us* __restrict__ C, int M, int N, int K, int heads,
    const float* __restrict__ a_src, const float* __restrict__ a_dst,
    float* __restrict__ al_s, float* __restrict__ al_d) {
  __shared__ us smem[4][128][40];
  int t = threadIdx.x;
  int m0 = blockIdx.x * 128;
  int n0 = blockIdx.y * 128;
  int w = t >> 6, l = t & 63;
  int wr = w >> 1, wc = w & 1;
  int l15 = l & 15, g = l >> 4;

  f32x4 acc[4][4] = {};

  for (int kb = 0; kb < K; kb += 32) {
    us8 z = {};
    #pragma unroll
    for (int i = 0; i < 2; i++) {
      int slot = i * 256 + t;
      int row = slot >> 2, kq = slot & 3;
      size_t gi = (size_t)(m0 + row) * K + kb + kq * 8;
      bool ok = (m0 + row) < M;
      *(us8*)&smem[0][row][kq * 8] = ok ? *(const us8*)&Agh[gi] : z;
      *(us8*)&smem[1][row][kq * 8] = ok ? *(const us8*)&Agl[gi] : z;
    }
    #pragma unroll
    for (int i = 0; i < 2; i++) {
      int slot = i * 256 + t;
      int n = slot >> 2, kq = slot & 3;
      size_t gi = (size_t)(n0 + n) * K + kb + kq * 8;
      *(us8*)&smem[2][n][kq * 8] = *(const us8*)&Bth[gi];
      *(us8*)&smem[3][n][kq * 8] = *(const us8*)&Btl[gi];
    }
    __syncthreads();

    bf16x8 af[4], al4[4], bf[4], bl4[4];
    #pragma unroll
    for (int i = 0; i < 4; i++) {
      af[i]  = *(const bf16x8*)&smem[0][wr * 64 + i * 16 + l15][g * 8];
      al4[i] = *(const bf16x8*)&smem[1][wr * 64 + i * 16 + l15][g * 8];
      bf[i]  = *(const bf16x8*)&smem[2][wc * 64 + i * 16 + l15][g * 8];
      bl4[i] = *(const bf16x8*)&smem[3][wc * 64 + i * 16 + l15][g * 8];
    }
    #pragma unroll
    for (int i = 0; i < 4; i++)
      #pragma unroll
      for (int j = 0; j < 4; j++) {
        acc[i][j] = __builtin_amdgcn_mfma_f32_16x16x32_bf16(af[i], bf[j], acc[i][j], 0, 0, 0);
        acc[i][j] = __builtin_amdgcn_mfma_f32_16x16x32_bf16(af[i], bl4[j], acc[i][j], 0, 0, 0);
        acc[i][j] = __builtin_amdgcn_mfma_f32_16x16x32_bf16(al4[i], bf[j], acc[i][j], 0, 0, 0);
      }
    __syncthreads();
  }

  // stage C tile in LDS, then us8 coalesced stores
  us* ct = &smem[0][0][0];  // 128x128 us = 32 KB
  #pragma unroll
  for (int i = 0; i < 4; i++)
    #pragma unroll
    for (int j = 0; j < 4; j++)
      #pragma unroll
      for (int r = 0; r < 4; r++) {
        int row = wr * 64 + i * 16 + g * 4 + r;
        int col = wc * 64 + j * 16 + l15;
        ct[row * 128 + col] = bf16rn(acc[i][j][r]);
      }
  __syncthreads();
  #pragma unroll
  for (int q = 0; q < 8; q++) {
    int slot = q * 256 + t;
    int row = slot >> 4, col8 = slot & 15;
    if (m0 + row < M) {
      us8 v = *(const us8*)&ct[row * 128 + col8 * 8];
      *(us8*)&C[(size_t)(m0 + row) * N + n0 + col8 * 8] = v;
    }
  }

  // fused logits from the LDS tile (pre-bias h values)
  if (heads == 4) {
    // this block's 128 cols = heads {2*by, 2*by+1}, each 64 ch, fully in-tile
    int r = t & 127, hs = t >> 7;
    int row = m0 + r;
    if (row < M) {
      int head = blockIdx.y * 2 + hs;
      const float* as = &a_src[head * 64];
      const float* ad = &a_dst[head * 64];
      float ss = 0.f, sd = 0.f;
      #pragma unroll
      for (int k8 = 0; k8 < 8; k8++) {
        us8 v = *(const us8*)&ct[r * 128 + hs * 64 + k8 * 8];
        #pragma unroll
        for (int j = 0; j < 8; j++) {
          float f = bf2f(v[j]);
          ss += f * as[k8 * 8 + j];
          sd += f * ad[k8 * 8 + j];
        }
      }
      al_s[row * 4 + head] = ss;
      al_d[row * 4 + head] = sd;
    }
  } else if (heads == 1) {
    // single head, all 128 ch in-tile; threads 0..127 do full dots
    if (t < 128) {
      int row = m0 + t;
      if (row < M) {
        float ss = 0.f, sd = 0.f;
        #pragma unroll
        for (int k8 = 0; k8 < 16; k8++) {
          us8 v = *(const us8*)&ct[t * 128 + k8 * 8];
          #pragma unroll
          for (int j = 0; j < 8; j++) {
            float f = bf2f(v[j]);
            ss += f * a_src[k8 * 8 + j];
            sd += f * a_dst[k8 * 8 + j];
          }
        }
        al_s[row] = ss;
        al_d[row] = sd;
      }
    }
  }
}

// ---------------- CSR build ----------------
__global__ __launch_bounds__(256) void count_kernel(const int* __restrict__ dst,
                                                    int* __restrict__ cnt) {
  int e = blockIdx.x * 256 + threadIdx.x;
  if (e < N_EDGES) atomicAdd(&cnt[dst[e]], 1);
}

__global__ __launch_bounds__(256) void scan1_kernel(const int* __restrict__ cnt,
                                                    int* __restrict__ itmp,
                                                    int* __restrict__ bsum) {
  int i = blockIdx.x * 256 + threadIdx.x;
  int v = (i < N_NODES) ? cnt[i] : 0;
  int lane = threadIdx.x & 63, w = threadIdx.x >> 6;
  int s = v;
  #pragma unroll
  for (int off = 1; off < 64; off <<= 1) {
    int tv = __shfl_up(s, off);
    if (lane >= off) s += tv;
  }
  __shared__ int wsum[4];
  if (lane == 63) wsum[w] = s;
  __syncthreads();
  int add = 0;
  for (int p = 0; p < w; p++) add += wsum[p];
  s += add;
  if (i < N_NODES) itmp[i] = s;
  if (threadIdx.x == 255) bsum[blockIdx.x] = s;
}

// scan3 with fused block-offset reduction (replaces scan2)
__global__ __launch_bounds__(256) void scan3_kernel(const int* __restrict__ cnt,
                                                    const int* __restrict__ itmp,
                                                    const int* __restrict__ bsum,
                                                    int* __restrict__ rowst,
                                                    int* __restrict__ cursor,
                                                    int nb) {
  int t = threadIdx.x;
  int lane = t & 63, w = t >> 6;
  // boff = sum of bsum[0 .. blockIdx.x-1]
  int v = (t < nb && t < blockIdx.x) ? bsum[t] : 0;
  int s = v;
  #pragma unroll
  for (int off = 1; off < 64; off <<= 1) s += __shfl_xor(s, off);
  __shared__ int partial[4];
  if (lane == 0) partial[w] = s;
  __syncthreads();
  int boff = partial[0] + partial[1] + partial[2] + partial[3];
  int i = blockIdx.x * 256 + t;
  if (i < N_NODES) {
    int excl = itmp[i] - cnt[i] + boff;
    rowst[i] = excl;
    cursor[i] = excl;
  }
  if (i == 0) rowst[N_NODES] = N_EDGES;
}

__global__ __launch_bounds__(256) void scatter_kernel(
    const int* __restrict__ src, const int* __restrict__ dst,
    int* __restrict__ cursor, int* __restrict__ csr_src) {
  int e = blockIdx.x * 256 + threadIdx.x;
  if (e < N_EDGES) {
    int p = atomicAdd(&cursor[dst[e]], 1);
    csr_src[p] = src[e];
  }
}

// ---------------- layer-1 aggregation: batch-4 readlane gathers ----------------
__global__ __launch_bounds__(256) void agg1_kernel(
    const us* __restrict__ h1b, const float* __restrict__ al_s,
    const float* __restrict__ al_d, const int* __restrict__ rowst,
    const int* __restrict__ csrc, const float* __restrict__ b1,
    us* __restrict__ outh, us* __restrict__ outl) {
  int d = (blockIdx.x * 256 + threadIdx.x) >> 6;
  int lane = threadIdx.x & 63;
  if (d >= N_NODES) return;
  int head = lane >> 4;
  int c0 = lane * 4;
  int wsel = lane & 48;
  float ald = al_d[d * 4 + head];
  float wsum = 0.f, a0 = 0.f, a1 = 0.f, a2 = 0.f, a3 = 0.f;
  {  // self-loop
    float v = al_s[d * 4 + head] + ald;
    v = v > 0.f ? v : NEG * v;
    float w = __expf(v);
    us4 hv = *(const us4*)&h1b[(size_t)d * 256 + c0];
    wsum += w;
    a0 += w * bf2f(hv[0]); a1 += w * bf2f(hv[1]);
    a2 += w * bf2f(hv[2]); a3 += w * bf2f(hv[3]);
  }
  int beg = rowst[d], end = rowst[d + 1];
  int j = beg;
  for (; j + 16 <= end; j += 16) {
    int el = lane & 15;
    int sv = csrc[j + el];
    float v = al_s[sv * 4 + head] + ald;
    v = v > 0.f ? v : NEG * v;
    float wv = __expf(v);
    #pragma unroll
    for (int q = 0; q < 16; q += 4) {
      int s0 = __builtin_amdgcn_readlane(sv, q + 0);
      int s1 = __builtin_amdgcn_readlane(sv, q + 1);
      int s2 = __builtin_amdgcn_readlane(sv, q + 2);
      int s3 = __builtin_amdgcn_readlane(sv, q + 3);
      us4 h0 = *(const us4*)&h1b[(size_t)(unsigned)s0 * 256 + c0];
      us4 h1 = *(const us4*)&h1b[(size_t)(unsigned)s1 * 256 + c0];
      us4 h2 = *(const us4*)&h1b[(size_t)(unsigned)s2 * 256 + c0];
      us4 h3 = *(const us4*)&h1b[(size_t)(unsigned)s3 * 256 + c0];
      float w0 = __shfl(wv, q + 0 + wsel);
      float w1 = __shfl(wv, q + 1 + wsel);
      float w2 = __shfl(wv, q + 2 + wsel);
      float w3 = __shfl(wv, q + 3 + wsel);
      wsum += w0 + w1 + w2 + w3;
      a0 += w0 * bf2f(h0[0]) + w1 * bf2f(h1[0]) + w2 * bf2f(h2[0]) + w3 * bf2f(h3[0]);
      a1 += w0 * bf2f(h0[1]) + w1 * bf2f(h1[1]) + w2 * bf2f(h2[1]) + w3 * bf2f(h3[1]);
      a2 += w0 * bf2f(h0[2]) + w1 * bf2f(h1[2]) + w2 * bf2f(h2[2]) + w3 * bf2f(h3[2]);
      a3 += w0 * bf2f(h0[3]) + w1 * bf2f(h1[3]) + w2 * bf2f(h2[3]) + w3 * bf2f(h3[3]);
    }
  }
  int m = end - j;
  if (m > 0) {
    int el = lane & 15;
    int sv = csrc[j + (el < m ? el : 0)];
    float v = al_s[sv * 4 + head] + ald;
    v = v > 0.f ? v : NEG * v;
    float wv = __expf(v);
    for (int q = 0; q < m; q += 4) {
      int k0 = q, k1 = q + 1 < m ? q + 1 : 0, k2 = q + 2 < m ? q + 2 : 0,
          k3 = q + 3 < m ? q + 3 : 0;
      int s0 = __builtin_amdgcn_readlane(sv, k0);
      int s1 = __builtin_amdgcn_readlane(sv, k1);
      int s2 = __builtin_amdgcn_readlane(sv, k2);
      int s3 = __builtin_amdgcn_readlane(sv, k3);
      us4 h0 = *(const us4*)&h1b[(size_t)(unsigned)s0 * 256 + c0];
      us4 h1 = *(const us4*)&h1b[(size_t)(unsigned)s1 * 256 + c0];
      us4 h2 = *(const us4*)&h1b[(size_t)(unsigned)s2 * 256 + c0];
      us4 h3 = *(const us4*)&h1b[(size_t)(unsigned)s3 * 256 + c0];
      float w0 = __shfl(wv, k0 + wsel);
      float w1 = __shfl(wv, k1 + wsel);
      float w2 = __shfl(wv, k2 + wsel);
      float w3 = __shfl(wv, k3 + wsel);
      if (q + 1 >= m) w1 = 0.f;
      if (q + 2 >= m) w2 = 0.f;
      if (q + 3 >= m) w3 = 0.f;
      wsum += w0 + w1 + w2 + w3;
      a0 += w0 * bf2f(h0[0]) + w1 * bf2f(h1[0]) + w2 * bf2f(h2[0]) + w3 * bf2f(h3[0]);
      a1 += w0 * bf2f(h0[1]) + w1 * bf2f(h1[1]) + w2 * bf2f(h2[1]) + w3 * bf2f(h3[1]);
      a2 += w0 * bf2f(h0[2]) + w1 * bf2f(h1[2]) + w2 * bf2f(h2[2]) + w3 * bf2f(h3[2]);
      a3 += w0 * bf2f(h0[3]) + w1 * bf2f(h1[3]) + w2 * bf2f(h2[3]) + w3 * bf2f(h3[3]);
    }
  }
  float inv = 1.f / (wsum + 1e-16f);
  float4 bb = *(const float4*)&b1[c0];
  float o[4] = {a0 * inv + bb.x, a1 * inv + bb.y, a2 * inv + bb.z, a3 * inv + bb.w};
  us4 oh, ol;
  #pragma unroll
  for (int i = 0; i < 4; i++) {
    float e = o[i] > 0.f ? o[i] : expm1f(o[i]);
    us h = bf16rn(e);
    oh[i] = h;
    ol[i] = bf16rn(e - bf2f(h));
  }
  *(us4*)&outh[(size_t)d * 256 + c0] = oh;
  *(us4*)&outl[(size_t)d * 256 + c0] = ol;
}

// ---------------- layer-2 aggregation: batch-4 readlane gathers ----------------
__global__ __launch_bounds__(256) void agg2_kernel(
    const us* __restrict__ h2b, const float* __restrict__ al_s,
    const float* __restrict__ al_d, const int* __restrict__ rowst,
    const int* __restrict__ csrc, const float* __restrict__ b2,
    float* __restrict__ out) {
  int d = (blockIdx.x * 256 + threadIdx.x) >> 6;
  int lane = threadIdx.x & 63;
  if (d >= N_NODES) return;
  int c0 = lane * 2;
  float ald = al_d[d];
  float wsum = 0.f, a0 = 0.f, a1 = 0.f;
  {  // self-loop
    float v = al_s[d] + ald;
    v = v > 0.f ? v : NEG * v;
    float w = __expf(v);
    us2 hv = *(const us2*)&h2b[(size_t)d * 128 + c0];
    wsum += w;
    a0 += w * bf2f(hv[0]); a1 += w * bf2f(hv[1]);
  }
  int beg = rowst[d], end = rowst[d + 1];
  int j = beg;
  for (; j + 64 <= end; j += 64) {
    int sv = csrc[j + lane];
    float v = al_s[sv] + ald;
    v = v > 0.f ? v : NEG * v;
    float wv = __expf(v);
    for (int q = 0; q < 64; q += 4) {
      int s0 = __builtin_amdgcn_readlane(sv, q + 0);
      int s1 = __builtin_amdgcn_readlane(sv, q + 1);
      int s2 = __builtin_amdgcn_readlane(sv, q + 2);
      int s3 = __builtin_amdgcn_readlane(sv, q + 3);
      us2 h0 = *(const us2*)&h2b[(size_t)(unsigned)s0 * 128 + c0];
      us2 h1 = *(const us2*)&h2b[(size_t)(unsigned)s1 * 128 + c0];
      us2 h2 = *(const us2*)&h2b[(size_t)(unsigned)s2 * 128 + c0];
      us2 h3 = *(const us2*)&h2b[(size_t)(unsigned)s3 * 128 + c0];
      float w0 = readlane_f(wv, q + 0);
      float w1 = readlane_f(wv, q + 1);
      float w2 = readlane_f(wv, q + 2);
      float w3 = readlane_f(wv, q + 3);
      wsum += w0 + w1 + w2 + w3;
      a0 += w0 * bf2f(h0[0]) + w1 * bf2f(h1[0]) + w2 * bf2f(h2[0]) + w3 * bf2f(h3[0]);
      a1 += w0 * bf2f(h0[1]) + w1 * bf2f(h1[1]) + w2 * bf2f(h2[1]) + w3 * bf2f(h3[1]);
    }
  }
  int m = end - j;
  if (m > 0) {
    int sv = csrc[j + (lane < m ? lane : 0)];
    float v = al_s[sv] + ald;
    v = v > 0.f ? v : NEG * v;
    float wv = __expf(v);
    for (int q = 0; q < m; q += 4) {
      int k0 = q, k1 = q + 1 < m ? q + 1 : 0, k2 = q + 2 < m ? q + 2 : 0,
          k3 = q + 3 < m ? q + 3 : 0;
      int s0 = __builtin_amdgcn_readlane(sv, k0);
      int s1 = __builtin_amdgcn_readlane(sv, k1);
      int s2 = __builtin_amdgcn_readlane(sv, k2);
      int s3 = __builtin_amdgcn_readlane(sv, k3);
      us2 h0 = *(const us2*)&h2b[(size_t)(unsigned)s0 * 128 + c0];
      us2 h1 = *(const us2*)&h2b[(size_t)(unsigned)s1 * 128 + c0];
      us2 h2 = *(const us2*)&h2b[(size_t)(unsigned)s2 * 128 + c0];
      us2 h3 = *(const us2*)&h2b[(size_t)(unsigned)s3 * 128 + c0];
      float w0 = readlane_f(wv, k0);
      float w1 = readlane_f(wv, k1);
      float w2 = readlane_f(wv, k2);
      float w3 = readlane_f(wv, k3);
      if (q + 1 >= m) w1 = 0.f;
      if (q + 2 >= m) w2 = 0.f;
      if (q + 3 >= m) w3 = 0.f;
      wsum += w0 + w1 + w2 + w3;
      a0 += w0 * bf2f(h0[0]) + w1 * bf2f(h1[0]) + w2 * bf2f(h2[0]) + w3 * bf2f(h3[0]);
      a1 += w0 * bf2f(h0[1]) + w1 * bf2f(h1[1]) + w2 * bf2f(h2[1]) + w3 * bf2f(h3[1]);
    }
  }
  float inv = 1.f / (wsum + 1e-16f);
  float2 bb = *(const float2*)&b2[c0];
  float o0 = a0 * inv + bb.x, o1 = a1 * inv + bb.y;
  o0 = o0 > 0.f ? o0 : expm1f(o0);
  o1 = o1 > 0.f ? o1 : expm1f(o1);
  *(float2*)&out[(size_t)d * 128 + c0] = make_float2(o0, o1);
}

// ---------------- pooling ----------------
#define PNPB 128
__global__ __launch_bounds__(256) void pool_kernel(const float* __restrict__ y,
                                                   const int* __restrict__ batch,
                                                   float* __restrict__ psum) {
  int t = threadIdx.x;
  int lane32 = t & 31;
  int sub = t >> 5;
  int base = blockIdx.x * PNPB + sub * (PNPB / 8);
  int nend = base + PNPB / 8;
  if (nend > N_NODES) nend = N_NODES;
  float4 acc = make_float4(0.f, 0.f, 0.f, 0.f);
  int curg = -1;
  for (int n = base; n < nend; ++n) {
    int g = batch[n];
    if (g != curg) {
      if (curg >= 0) {
        float* p = &psum[curg * 128 + lane32 * 4];
        atomicAdd(p + 0, acc.x); atomicAdd(p + 1, acc.y);
        atomicAdd(p + 2, acc.z); atomicAdd(p + 3, acc.w);
      }
      acc = make_float4(0.f, 0.f, 0.f, 0.f);
      curg = g;
    }
    float4 v = *(const float4*)&y[(size_t)n * 128 + lane32 * 4];
    acc.x += v.x; acc.y += v.y; acc.z += v.z; acc.w += v.w;
  }
  if (curg >= 0) {
    float* p = &psum[curg * 128 + lane32 * 4];
    atomicAdd(p + 0, acc.x); atomicAdd(p + 1, acc.y);
    atomicAdd(p + 2, acc.z); atomicAdd(p + 3, acc.w);
  }
}

// ---------------- mean + FC + ReLU ----------------
__global__ __launch_bounds__(128) void fc_kernel(
    const float* __restrict__ psum, const int* __restrict__ batch,
    const float* __restrict__ fcW, const float* __restrict__ fcb,
    float* __restrict__ out) {
  __shared__ float pr[128];
  __shared__ int bounds[2];
  int g = blockIdx.x, c = threadIdx.x;
  if (c < 2) {
    int target = g + c;
    int lo = 0, hi = N_NODES;
    while (lo < hi) {
      int mid = (lo + hi) >> 1;
      if (batch[mid] < target) lo = mid + 1; else hi = mid;
    }
    bounds[c] = lo;
  }
  __syncthreads();
  float cnt = (float)(bounds[1] - bounds[0]);
  cnt = cnt > 1.f ? cnt : 1.f;
  pr[c] = psum[g * 128 + c] / cnt;
  __syncthreads();
  float s = fcb[c];
  #pragma unroll 8
  for (int k = 0; k < 128; k++) s += pr[k] * fcW[k * 128 + c];
  out[g * 128 + c] = fmaxf(s, 0.f);
}

extern "C" void kernel_launch(void* const* d_in, const int* in_sizes, int n_in,
                              void* d_out, int out_size, void* d_ws,
                              size_t ws_size, hipStream_t stream) {
  const float* x      = (const float*)d_in[0];
  const int*   ei     = (const int*)d_in[1];
  const int*   batch  = (const int*)d_in[2];
  const float* W1     = (const float*)d_in[3];
  const float* a1_src = (const float*)d_in[4];
  const float* a1_dst = (const float*)d_in[5];
  const float* b1     = (const float*)d_in[6];
  const float* W2     = (const float*)d_in[7];
  const float* a2_src = (const float*)d_in[8];
  const float* a2_dst = (const float*)d_in[9];
  const float* b2     = (const float*)d_in[10];
  const float* fc_W   = (const float*)d_in[11];
  const float* fc_b   = (const float*)d_in[12];
  float* out = (float*)d_out;

  const int* srcp = ei;
  const int* dstp = ei + N_EDGES;
  const int NB = (N_NODES + 255) / 256;  // 196

  // ---- workspace layout ----
  float* y    = (float*)d_ws;                 // [50000*128]
  float* al1s = y + (size_t)N_NODES * 128;
  float* al1d = al1s + N_NODES * 4;
  float* al2s = al1d + N_NODES * 4;
  float* al2d = al2s + N_NODES;
  float* psum = al2d + N_NODES;               // [64*128]
  us* xh   = (us*)(psum + N_GRAPHS * 128);    // [50000*128]
  us* xl   = xh + (size_t)N_NODES * 128;
  us* x2h  = xl + (size_t)N_NODES * 128;      // [50000*256]
  us* x2l  = x2h + (size_t)N_NODES * 256;
  us* h1b  = x2l + (size_t)N_NODES * 256;     // [50000*256]
  us* h2b  = h1b + (size_t)N_NODES * 256;     // [50000*128]
  us* w1th = h2b + (size_t)N_NODES * 128;
  us* w1tl = w1th + 256 * 128;
  us* w2th = w1tl + 256 * 128;
  us* w2tl = w2th + 128 * 256;
  int* cnt    = (int*)(w2tl + 128 * 256);     // [50000]
  int* bsum   = cnt + N_NODES;
  int* boff   = bsum + 256;
  int* itmp   = boff + 256;
  int* rowst  = itmp + N_NODES;               // [50001]
  int* cursor = rowst + N_NODES + 8;
  int* csrc   = cursor + N_NODES;             // [800000]
  size_t needed = (size_t)((char*)(csrc + N_EDGES) - (char*)d_ws);
  if (ws_size < needed) return;

  // prep: xsplit + convW + zero cnt/psum (blocks partitioned inside)
  prep_kernel<<<6702, 256, 0, stream>>>(x, xh, xl, W1, W2, w1th, w1tl, w2th,
                                        w2tl, cnt, psum);

  // CSR build
  count_kernel<<<(N_EDGES + 255) / 256, 256, 0, stream>>>(dstp, cnt);
  scan1_kernel<<<NB, 256, 0, stream>>>(cnt, itmp, bsum);
  scan3_kernel<<<NB, 256, 0, stream>>>(cnt, itmp, bsum, rowst, cursor, NB);
  scatter_kernel<<<(N_EDGES + 255) / 256, 256, 0, stream>>>(srcp, dstp, cursor, csrc);

  // layer 1 (GEMM + fused logits)
  gemm_bf16x3<<<dim3(391, 2), 256, 0, stream>>>(xh, xl, w1th, w1tl, h1b,
                                                N_NODES, 256, 128, 4, a1_src,
                                                a1_dst, al1s, al1d);
  agg1_kernel<<<(N_NODES * 64 + 255) / 256, 256, 0, stream>>>(
      h1b, al1s, al1d, rowst, csrc, b1, x2h, x2l);

  // layer 2 (GEMM + fused logits)
  gemm_bf16x3<<<dim3(391, 1), 256, 0, stream>>>(x2h, x2l, w2th, w2tl, h2b,
                                                N_NODES, 128, 256, 1, a2_src,
                                                a2_dst, al2s, al2d);
  agg2_kernel<<<(N_NODES * 64 + 255) / 256, 256, 0, stream>>>(
      h2b, al2s, al2d, rowst, csrc, b2, y);

  // pool + fc
  pool_kernel<<<(N_NODES + PNPB - 1) / PNPB, 256, 0, stream>>>(y, batch, psum);
  fc_kernel<<<N_GRAPHS, 128, 0, stream>>>(psum, batch, fc_W, fc_b, out);
}